// Round 7
// baseline (816.435 us; speedup 1.0000x reference)
//
#include <hip/hip_runtime.h>
#include <hip/hip_bf16.h>
#include <math.h>

#define N_NODES 50000
#define MP      50048          // 391 * 128, padded row count
#define E_EDGES 500000
#define EPRIME  (E_EDGES + N_NODES)
#define HID     256
#define PRE_IN  1024
#define OUT_DIM 64
#define NHEAD   4
#define DHEAD   64
#define LAYERS  2
#define NTYPES  2

#define SCAN_NBLK 49                     // ceil(50000/1024)
#define NPAD      (SCAN_NBLK * 1024)     // 50176

typedef __attribute__((ext_vector_type(8))) short short8v;
typedef __attribute__((ext_vector_type(4))) float f32x4;
typedef _Float16 h2v __attribute__((ext_vector_type(2)));
typedef _Float16 h8v __attribute__((ext_vector_type(8)));

__device__ __forceinline__ ushort f2bf(float f) {
  uint u = __float_as_uint(f);
  u += 0x7FFF + ((u >> 16) & 1);          // RNE
  return (ushort)(u >> 16);
}
__device__ __forceinline__ float bf2f(ushort u) {
  return __uint_as_float(((uint)u) << 16);
}

#define WAITV3 asm volatile("s_waitcnt vmcnt(3)" ::: "memory")
#define WAITV0 asm volatile("s_waitcnt vmcnt(0)" ::: "memory")
#define WAITLG asm volatile("s_waitcnt lgkmcnt(0)" ::: "memory")
#define SCHEDB __builtin_amdgcn_sched_barrier(0)
#define BARRIER __builtin_amdgcn_s_barrier()

// ------------------------------------------------------------- bf16 MFMA GEMM
// C[M,N] = op(A[M,K] @ Bt[N,K]^T + bias(+bias2)); Bt bf16 K-major, rows padded.
// A: bf16 K-major (AF32=false) or f32 K-major (AF32=true, rows >= M read as 0).
// BM=128, BN=64, BK=32; 4 waves, wave-tile 64x32 (acc[4][2], 8 MFMA/K-step).
// T1: bijective XCD-chunked blockIdx swizzle (m204).
// T3/T4: triple-buffered ring pipeline, staging issued 2 tiles ahead, raw
//   s_barrier + counted s_waitcnt vmcnt(3) (never drain to 0 in steady state)
//   -- round 6 showed the 2-barrier drain loop exposes full HBM/L3 latency
//   every K-step (pre0: 1.06 TB/s, 15% VALU, 41% occ, nothing busy).
// LDS layout byte = row*64 + (kc ^ ((row>>1)&3))*16 (XOR swizzle on both sides).
template<bool AF32>
__global__ __launch_bounds__(256) void gemm_k(
    const void* __restrict__ Ap,
    const ushort* __restrict__ Bt,
    int K, int M, int N,
    float*  __restrict__ Cf,          // f32 out (or null)
    ushort* __restrict__ Cb,          // 16-bit out (or null)
    const float* __restrict__ bias,   // [N] or null
    const float* __restrict__ bias2,  // [N] or null (added too)
    int do_relu, int out_f16)         // out_f16: Cb holds fp16 instead of bf16
{
  __shared__ ushort As[3][128 * 32];  // 3 x 8 KB
  __shared__ ushort Bs[3][64 * 32];   // 3 x 4 KB
  const int tid = threadIdx.x;
  const int l   = tid & 63;
  const int w   = tid >> 6;
  const int wm  = w & 1;              // row half (64 rows)
  const int wn  = w >> 1;             // col quarter (32 cols)

  // ---- T1: bijective XCD-chunked swizzle (m204)
  const int nwg  = gridDim.x * gridDim.y;
  const int orig = blockIdx.y * gridDim.x + blockIdx.x;
  const int qq   = nwg >> 3, rr = nwg & 7;
  const int xcd  = orig & 7;
  const int wgid = ((xcd < rr) ? xcd * (qq + 1) : rr * (qq + 1) + (xcd - rr) * qq)
                   + (orig >> 3);
  const int bm = (wgid / gridDim.x) * 128;
  const int bn = (wgid % gridDim.x) * 64;

  f32x4 acc[4][2];
#pragma unroll
  for (int m = 0; m < 4; m++)
#pragma unroll
    for (int n = 0; n < 2; n++) acc[m][n] = (f32x4){0.f, 0.f, 0.f, 0.f};

  const int srow  = l >> 2;   // 0..15
  const int sslot = l & 3;    // kc slot
  const int nt    = K >> 5;   // K-tiles (>= 8 for all our shapes)

  // A staging geometry (2 rows per thread)
  int  arow[2], akc[2];
  uint aoff[2];
#pragma unroll
  for (int i = 0; i < 2; i++) {
    arow[i] = w * 32 + i * 16 + srow;
    akc[i]  = sslot ^ ((arow[i] >> 1) & 3);
    aoff[i] = (uint)arow[i] * 64 + (uint)sslot * 16;
  }
  // B staging geometry: one 16B slot per thread, dest = tid*16 (wave-linear)
  const int brow  = tid >> 2;        // 0..63
  const int bslot = tid & 3;
  const int bkc   = bslot ^ ((brow >> 1) & 3);

  float4 pf[2][2];
  if constexpr (AF32) {
#pragma unroll
    for (int i = 0; i < 2; i++) {
      pf[i][0] = make_float4(0.f, 0.f, 0.f, 0.f);
      pf[i][1] = make_float4(0.f, 0.f, 0.f, 0.f);
    }
  }

#define STAGE_B(t, buf)                                                        \
  {                                                                            \
    const ushort* gb = Bt + (size_t)(bn + brow) * K + ((t) << 5) + bkc * 8;    \
    __builtin_amdgcn_global_load_lds(                                          \
        (const __attribute__((address_space(1))) uint*)gb,                     \
        (__attribute__((address_space(3))) uint*)((char*)Bs[buf] + tid * 16),  \
        16, 0, 0);                                                             \
  }
#define STAGE_A16(t, buf)                                                      \
  _Pragma("unroll")                                                            \
  for (int i = 0; i < 2; i++) {                                                \
    const ushort* ga = (const ushort*)Ap + (size_t)(bm + arow[i]) * K +        \
                       ((t) << 5) + akc[i] * 8;                                \
    __builtin_amdgcn_global_load_lds(                                          \
        (const __attribute__((address_space(1))) uint*)ga,                     \
        (__attribute__((address_space(3))) uint*)((char*)As[buf] + aoff[i]),   \
        16, 0, 0);                                                             \
  }
#define LOAD_A32(t)                                                            \
  _Pragma("unroll")                                                            \
  for (int i = 0; i < 2; i++) {                                                \
    if (bm + arow[i] < M) {                                                    \
      const float* ga = (const float*)Ap + (size_t)(bm + arow[i]) * K +        \
                        ((t) << 5) + akc[i] * 8;                               \
      pf[i][0] = *reinterpret_cast<const float4*>(ga);                         \
      pf[i][1] = *reinterpret_cast<const float4*>(ga + 4);                     \
    }                                                                          \
  }
#define WRITE_A32(buf)                                                         \
  _Pragma("unroll")                                                            \
  for (int i = 0; i < 2; i++) {                                                \
    short8v s;                                                                 \
    s[0] = (short)f2bf(pf[i][0].x); s[1] = (short)f2bf(pf[i][0].y);            \
    s[2] = (short)f2bf(pf[i][0].z); s[3] = (short)f2bf(pf[i][0].w);            \
    s[4] = (short)f2bf(pf[i][1].x); s[5] = (short)f2bf(pf[i][1].y);            \
    s[6] = (short)f2bf(pf[i][1].z); s[7] = (short)f2bf(pf[i][1].w);            \
    *reinterpret_cast<short8v*>((char*)As[buf] + aoff[i]) = s;                 \
  }

  // ---- prologue: tile 0 fully staged; tile 1 staging left in flight
  if constexpr (AF32) {
    STAGE_B(0, 0);
    LOAD_A32(0);
    WRITE_A32(0);                 // compiler waits pf loads -> drains B(0) too
    STAGE_B(1, 1);
    LOAD_A32(1);                  // consumed by WRITE_A32 at iter 0
    WAITLG; SCHEDB; BARRIER; SCHEDB;
  } else {
    STAGE_B(0, 0); STAGE_A16(0, 0);
    STAGE_B(1, 1); STAGE_A16(1, 1);
    WAITV3;                       // drain tile 0 (3 ops), leave tile 1 in flight
    SCHEDB; BARRIER; SCHEDB;
  }

  int rd = 0;
  for (int t = 0; t < nt; t++) {
    int wr = rd + 1; if (wr == 3) wr = 0;    // (t+1)%3
    int st = wr + 1; if (st == 3) st = 0;    // (t+2)%3

    if constexpr (AF32) {
      if (t + 1 < nt) WRITE_A32(wr);         // tile t+1 (pf loaded at t-1)
      if (t + 2 < nt) { STAGE_B(t + 2, st); LOAD_A32(t + 2); }
    } else {
      if (t + 2 < nt) { STAGE_B(t + 2, st); STAGE_A16(t + 2, st); }
    }

    short8v a[4], b[2];
#pragma unroll
    for (int m = 0; m < 4; m++) {
      const int row = wm * 64 + m * 16 + (l & 15);
      const int kc  = (l >> 4) ^ ((row >> 1) & 3);
      a[m] = *(const short8v*)((const char*)As[rd] + row * 64 + kc * 16);
    }
#pragma unroll
    for (int n = 0; n < 2; n++) {
      const int row = wn * 32 + n * 16 + (l & 15);
      const int kc  = (l >> 4) ^ ((row >> 1) & 3);
      b[n] = *(const short8v*)((const char*)Bs[rd] + row * 64 + kc * 16);
    }
#pragma unroll
    for (int m = 0; m < 4; m++)
#pragma unroll
      for (int n = 0; n < 2; n++)
        acc[m][n] = __builtin_amdgcn_mfma_f32_16x16x32_bf16(a[m], b[n], acc[m][n], 0, 0, 0);

    if (t + 1 < nt) {
      if constexpr (AF32) {
        WAITLG;                   // ds_write of tile t+1 drained; B-drain implied
      } else {
        if (t + 2 < nt) { WAITV3; }  // drain tile t+1 (oldest 3), leave t+2
        else            { WAITV0; }
      }
      SCHEDB; BARRIER; SCHEDB;
    }
    rd = wr;
  }

  // epilogue: C/D map col=lane&15, row=(lane>>4)*4+reg
  const int crow0 = bm + wm * 64 + (l >> 4) * 4;
  const int ccol0 = bn + wn * 32 + (l & 15);
#pragma unroll
  for (int m = 0; m < 4; m++) {
#pragma unroll
    for (int j = 0; j < 4; j++) {
      const int grow = crow0 + m * 16 + j;
      if (grow < M) {
#pragma unroll
        for (int n = 0; n < 2; n++) {
          const int gcol = ccol0 + n * 16;
          if (gcol < N) {
            float v = acc[m][n][j];
            if (bias)  v += bias[gcol];
            if (bias2) v += bias2[gcol];
            if (do_relu) v = fmaxf(v, 0.f);
            if (Cf) Cf[(size_t)grow * N + gcol] = v;
            else if (out_f16) {
              _Float16 hv = (_Float16)v;
              Cb[(size_t)grow * N + gcol] = *(ushort*)&hv;
            } else {
              Cb[(size_t)grow * N + gcol] = f2bf(v);
            }
          }
        }
      }
    }
  }
}

// ------------------------------------------------------------ LayerNorm+ReLU
__global__ void ln_relu(const float* __restrict__ in, ushort* __restrict__ out,
                        const float* __restrict__ g, const float* __restrict__ be, int n)
{
  int gid = blockIdx.x * blockDim.x + threadIdx.x;
  int row = gid >> 6;
  int lane = threadIdx.x & 63;
  if (row >= n) return;
  float4 v = *reinterpret_cast<const float4*>(in + (size_t)row * HID + lane * 4);
  float s = v.x + v.y + v.z + v.w;
  float ss = v.x * v.x + v.y * v.y + v.z * v.z + v.w * v.w;
#pragma unroll
  for (int o = 1; o < 64; o <<= 1) { s += __shfl_xor(s, o); ss += __shfl_xor(ss, o); }
  float mu = s * (1.f / 256.f);
  float var = ss * (1.f / 256.f) - mu * mu;
  float inv = rsqrtf(var + 1e-5f);
  float4 gg = *reinterpret_cast<const float4*>(g + lane * 4);
  float4 bb = *reinterpret_cast<const float4*>(be + lane * 4);
  ushort4 o4;
  o4.x = f2bf(fmaxf((v.x - mu) * inv * gg.x + bb.x, 0.f));
  o4.y = f2bf(fmaxf((v.y - mu) * inv * gg.y + bb.y, 0.f));
  o4.z = f2bf(fmaxf((v.z - mu) * inv * gg.z + bb.z, 0.f));
  o4.w = f2bf(fmaxf((v.w - mu) * inv * gg.w + bb.w, 0.f));
  *reinterpret_cast<ushort4*>(out + (size_t)row * HID + lane * 4) = o4;
}

// ------------------------------------------------------------- CSR building
__global__ void csr_count2(const int* __restrict__ ei0, const int* __restrict__ ei1,
                           int* __restrict__ cnt0, int* __restrict__ cnt1)
{
  int e = blockIdx.x * blockDim.x + threadIdx.x;
  if (e >= 2 * EPRIME) return;
  int type = e >= EPRIME;
  int i = type ? e - EPRIME : e;
  const int* ei = type ? ei1 : ei0;
  int* cnt = type ? cnt1 : cnt0;
  int d = (i < E_EDGES) ? ei[E_EDGES + i] : (i - E_EDGES);
  atomicAdd(&cnt[d], 1);
}

// --- hierarchical exclusive scan over cnt0,cnt1 (padded to NPAD with zeros)
__global__ __launch_bounds__(256) void scan_p1(const int* __restrict__ cnt0,
                                               const int* __restrict__ cnt1,
                                               int* __restrict__ bsums)
{
  int type = blockIdx.x >= SCAN_NBLK;
  int blk = type ? blockIdx.x - SCAN_NBLK : blockIdx.x;
  const int* cnt = type ? cnt1 : cnt0;
  int4 v = reinterpret_cast<const int4*>(cnt)[blk * 256 + threadIdx.x];
  int s = v.x + v.y + v.z + v.w;
#pragma unroll
  for (int o = 1; o < 64; o <<= 1) s += __shfl_xor(s, o);
  __shared__ int wt[4];
  if ((threadIdx.x & 63) == 0) wt[threadIdx.x >> 6] = s;
  __syncthreads();
  if (threadIdx.x == 0) bsums[blockIdx.x] = wt[0] + wt[1] + wt[2] + wt[3];
}

__global__ void scan_p2(const int* __restrict__ bsums, int* __restrict__ boffs,
                        int* __restrict__ offs0, int* __restrict__ offs1)
{
  int t = threadIdx.x;
  if (t < 2) {
    int run = 0;
    for (int i = 0; i < SCAN_NBLK; i++) {
      boffs[t * SCAN_NBLK + i] = run;
      run += bsums[t * SCAN_NBLK + i];
    }
  }
  if (t == 2) offs0[N_NODES] = EPRIME;
  if (t == 3) offs1[N_NODES] = EPRIME;
}

__global__ __launch_bounds__(256) void scan_p3(
    const int* __restrict__ cnt0, const int* __restrict__ cnt1,
    const int* __restrict__ boffs,
    int* __restrict__ offs0, int* __restrict__ cur0,
    int* __restrict__ offs1, int* __restrict__ cur1)
{
  int type = blockIdx.x >= SCAN_NBLK;
  int blk = type ? blockIdx.x - SCAN_NBLK : blockIdx.x;
  const int* cnt = type ? cnt1 : cnt0;
  int* offs = type ? offs1 : offs0;
  int* cur  = type ? cur1 : cur0;
  const int tid = threadIdx.x, lane = tid & 63, wv = tid >> 6;
  int4 v = reinterpret_cast<const int4*>(cnt)[blk * 256 + tid];
  int e1 = v.x, e2 = e1 + v.y, e3 = e2 + v.z, T = e3 + v.w;
  int incl = T;
#pragma unroll
  for (int o = 1; o < 64; o <<= 1) {
    int nb = __shfl_up(incl, o);
    if (lane >= o) incl += nb;
  }
  __shared__ int wt[4];
  if (lane == 63) wt[wv] = incl;
  __syncthreads();
  int wexcl = 0;
  for (int i = 0; i < wv; i++) wexcl += wt[i];
  int base = boffs[blockIdx.x] + wexcl + (incl - T);
  int idx = blk * 1024 + tid * 4;
  int4 o4 = make_int4(base, base + e1, base + e2, base + e3);
  if (idx + 3 < N_NODES) {
    reinterpret_cast<int4*>(offs)[idx >> 2] = o4;
    reinterpret_cast<int4*>(cur)[idx >> 2] = o4;
  } else {
    if (idx + 0 < N_NODES) { offs[idx + 0] = o4.x; cur[idx + 0] = o4.x; }
    if (idx + 1 < N_NODES) { offs[idx + 1] = o4.y; cur[idx + 1] = o4.y; }
    if (idx + 2 < N_NODES) { offs[idx + 2] = o4.z; cur[idx + 2] = o4.z; }
    if (idx + 3 < N_NODES) { offs[idx + 3] = o4.w; cur[idx + 3] = o4.w; }
  }
}

__global__ void csr_scatter2(const int* __restrict__ ei0, const int* __restrict__ ei1,
                             int* __restrict__ cur0, int* __restrict__ cur1,
                             int* __restrict__ csr0, int* __restrict__ csr1)
{
  int e = blockIdx.x * blockDim.x + threadIdx.x;
  if (e >= 2 * EPRIME) return;
  int type = e >= EPRIME;
  int i = type ? e - EPRIME : e;
  const int* ei = type ? ei1 : ei0;
  int* cur = type ? cur1 : cur0;
  int* csr = type ? csr1 : csr0;
  int d = (i < E_EDGES) ? ei[E_EDGES + i] : (i - E_EDGES);
  int s = (i < E_EDGES) ? ei[i] : (i - E_EDGES);
  int pos = atomicAdd(&cur[d], 1);
  csr[pos] = s;
}

__global__ void csr_sort2(const int* __restrict__ offs0, int* __restrict__ csr0,
                          const int* __restrict__ offs1, int* __restrict__ csr1)
{
  int d = blockIdx.x * blockDim.x + threadIdx.x;
  if (d >= 2 * N_NODES) return;
  int type = d >= N_NODES;
  int i = type ? d - N_NODES : d;
  const int* offs = type ? offs1 : offs0;
  int* csr = type ? csr1 : csr0;
  int b = offs[i], e = offs[i + 1];
  for (int p = b + 1; p < e; p++) {
    int v = csr[p];
    int j = p - 1;
    while (j >= b && csr[j] > v) { csr[j + 1] = csr[j]; j--; }
    csr[j + 1] = v;
  }
}

// --------------------------------- all weight transposes/casts in one kernel
#define WSEG0 262144              // W0t   [256][1024]
#define WSEG1 (WSEG0 + 65536)     // W1t   [256][256]
#define WSEG2 (WSEG1 + 524288)    // WcatT [L][1024][256]
#define WSEG3 (WSEG2 + 262144)    // projcatT [L][256][512]
#define WSEG4 (WSEG3 + 65536)     // hW0t  [256][256]
#define WSEG5 (WSEG4 + 32768)     // hW1t  [128][256]
__global__ void wtrans_all(const float* __restrict__ pre_W0, const float* __restrict__ pre_W1,
                           const float* __restrict__ Wl, const float* __restrict__ Wr,
                           const float* __restrict__ proj_W,
                           const float* __restrict__ head_W0, const float* __restrict__ head_W1,
                           ushort* __restrict__ W0t, ushort* __restrict__ W1t,
                           ushort* __restrict__ WcatT, ushort* __restrict__ projcatT,
                           ushort* __restrict__ hW0t, ushort* __restrict__ hW1t)
{
  int i = blockIdx.x * blockDim.x + threadIdx.x;
  if (i < WSEG0) {
    int nrow = i >> 10, k = i & 1023;
    W0t[i] = f2bf(pre_W0[(size_t)k * 256 + nrow]);
  } else if (i < WSEG1) {
    int j = i - WSEG0;
    int nrow = j >> 8, k = j & 255;
    W1t[j] = f2bf(pre_W1[(size_t)k * 256 + nrow]);
  } else if (i < WSEG2) {
    int j = i - WSEG1;
    int l = j >> 18;
    int rem = j & 262143;
    int c = rem >> 8, k = rem & 255;
    int t = c >> 9, half = (c >> 8) & 1, cc = c & 255;
    const float* W = half ? Wr : Wl;
    WcatT[j] = f2bf(W[(((size_t)l * NTYPES + t) * 256 + k) * 256 + cc]);
  } else if (i < WSEG3) {
    int j = i - WSEG2;
    int l = j >> 17;
    int rem = j & 131071;
    int n = rem >> 9, k = rem & 511;
    int t = k >> 8, kk = k & 255;
    projcatT[j] = f2bf(proj_W[(((size_t)l * NTYPES + t) * 256 + kk) * 256 + n]);
  } else if (i < WSEG4) {
    int j = i - WSEG3;
    int nrow = j >> 8, k = j & 255;
    hW0t[j] = f2bf(head_W0[(size_t)k * 256 + nrow]);
  } else if (i < WSEG5) {
    int j = i - WSEG4;
    int nrow = j >> 8, k = j & 255;
    hW1t[j] = (nrow < OUT_DIM) ? f2bf(head_W1[(size_t)k * OUT_DIM + nrow]) : (ushort)0;
  }
}

// --------------------------------------------------------- DPP 8-lane reduce
__device__ __forceinline__ float dpp8_sum(float p) {
  // sum over lanes (l & ~7)..(l | 7): xor1, xor2 (quad_perm), then half-mirror
  p += __int_as_float(__builtin_amdgcn_update_dpp(0, __float_as_int(p), 0xB1, 0xF, 0xF, true));
  p += __int_as_float(__builtin_amdgcn_update_dpp(0, __float_as_int(p), 0x4E, 0xF, 0xF, true));
  p += __int_as_float(__builtin_amdgcn_update_dpp(0, __float_as_int(p), 0x141, 0xF, 0xF, true));
  return p;
}

__device__ __forceinline__ h8v leaky8(h8v x) {
  const _Float16 c = (_Float16)0.2f;
  h8v y = x * c;
#if __has_builtin(__builtin_elementwise_max)
  return __builtin_elementwise_max(x, y);
#else
  h8v r;
#pragma unroll
  for (int i = 0; i < 8; i++) r[i] = x[i] > y[i] ? x[i] : y[i];
  return r;
#endif
}

__device__ __forceinline__ float dot8(h8v e, const h2v* a) {
  h2v e0 = {e[0], e[1]}, e1 = {e[2], e[3]}, e2 = {e[4], e[5]}, e3 = {e[6], e[7]};
#if __has_builtin(__builtin_amdgcn_fdot2)
  float s = __builtin_amdgcn_fdot2(e0, a[0], 0.f, false);
  s = __builtin_amdgcn_fdot2(e1, a[1], s, false);
  s = __builtin_amdgcn_fdot2(e2, a[2], s, false);
  s = __builtin_amdgcn_fdot2(e3, a[3], s, false);
  return s;
#else
  float s = 0.f;
#pragma unroll
  for (int i = 0; i < 8; i++) s += (float)e[i] * (float)a[i >> 1][i & 1];
  return s;
#endif
}

// ---------------------------------------------- GATv2: dst-centric online SM
// one wave per dst; lanes 0-31 = even edges, 32-63 = odd; 4 edges in flight.
// lane li owns 8 channels (16 B fp16); head = li>>3; DPP reduce over 8 lanes.
__global__ __launch_bounds__(256) void gat_edge3(
    const _Float16* __restrict__ xlr,   // [MP,1024] fp16
    const int* __restrict__ offs0, const int* __restrict__ csr0,
    const int* __restrict__ offs1, const int* __restrict__ csr1,
    const float* __restrict__ att,      // [2*256] layer base
    const float* __restrict__ bias,     // [2*256] layer base
    ushort* __restrict__ out, int nblk_per_type)
{
  const int type = blockIdx.x >= nblk_per_type;
  const int bid = type ? blockIdx.x - nblk_per_type : blockIdx.x;
  const int wid = (bid * 256 + threadIdx.x) >> 6;
  if (wid >= N_NODES) return;
  const int lane = threadIdx.x & 63;
  const int half = lane >> 5, li = lane & 31;
  const int* offs = type ? offs1 : offs0;
  const int* csr  = type ? csr1 : csr0;
  const int xl_col = type ? 512 : 0;

  // att (8 ch/lane) -> packed fp16 pairs
  const float* ap = att + type * 256 + li * 8;
  h2v a[4];
#pragma unroll
  for (int i = 0; i < 4; i++) {
    a[i][0] = (_Float16)ap[2 * i];
    a[i][1] = (_Float16)ap[2 * i + 1];
  }
  const h8v xr = *reinterpret_cast<const h8v*>(xlr + (size_t)wid * 1024 + xl_col + 256 + li * 8);

  const int beg = offs[wid], end = offs[wid + 1];
  const float L2E = 1.44269504f;
  float m = -1e30f, den = 0.f;
  float acc[8];
#pragma unroll
  for (int i = 0; i < 8; i++) acc[i] = 0.f;

  const int ng = (end - beg + 3) >> 2;
  for (int g = 0; g < ng; g++) {
    const int j0 = beg + 4 * g + half;
    const int j1 = j0 + 2;
    const bool v0 = j0 < end, v1 = j1 < end;
    const int s0 = csr[v0 ? j0 : beg];
    const int s1 = csr[v1 ? j1 : beg];
    const h8v hs0 = *reinterpret_cast<const h8v*>(xlr + (size_t)s0 * 1024 + xl_col + li * 8);
    const h8v hs1 = *reinterpret_cast<const h8v*>(xlr + (size_t)s1 * 1024 + xl_col + li * 8);
    float p0 = dpp8_sum(dot8(leaky8(hs0 + xr), a));
    float p1 = dpp8_sum(dot8(leaky8(hs1 + xr), a));
    if (!v0) p0 = -INFINITY;
    if (!v1) p1 = -INFINITY;
    const float pm = fmaxf(p0, p1);
    if (__any(pm > m + 4.f)) {           // defer-max rescale (rare)
      const float nm = fmaxf(m, pm);
      const float so = exp2f((m - nm) * L2E);
      den *= so;
#pragma unroll
      for (int i = 0; i < 8; i++) acc[i] *= so;
      m = nm;
    }
    const float w0 = exp2f((p0 - m) * L2E);
    const float w1 = exp2f((p1 - m) * L2E);
    den += w0 + w1;
#pragma unroll
    for (int i = 0; i < 8; i++) {
      acc[i] = fmaf((float)hs0[i], w0, acc[i]);
      acc[i] = fmaf((float)hs1[i], w1, acc[i]);
    }
  }

  // merge the two halves
  const float mo  = __shfl_xor(m, 32);
  const float dno = __shfl_xor(den, 32);
  const float ms = fmaxf(m, mo);
  const float fa = exp2f((m - ms) * L2E);
  const float fb = exp2f((mo - ms) * L2E);
  const float r = 1.f / (den * fa + dno * fb + 1e-16f);
  float of[8];
#pragma unroll
  for (int i = 0; i < 8; i++)
    of[i] = (acc[i] * fa + __shfl_xor(acc[i], 32) * fb) * r;

  if (half == 0) {
    const float* bp = bias + type * 256 + li * 8;
    uint4 o;
    uint pk[4];
#pragma unroll
    for (int i = 0; i < 4; i++) {
      const uint lo = f2bf(of[2 * i] + bp[2 * i]);
      const uint hi = f2bf(of[2 * i + 1] + bp[2 * i + 1]);
      pk[i] = lo | (hi << 16);
    }
    o.x = pk[0]; o.y = pk[1]; o.z = pk[2]; o.w = pk[3];
    *reinterpret_cast<uint4*>(out + (size_t)wid * 512 + type * 256 + li * 8) = o;
  }
}

// ----------------------------------------------------------------- launcher
extern "C" void kernel_launch(void* const* d_in, const int* in_sizes, int n_in,
                              void* d_out, int out_size, void* d_ws, size_t ws_size,
                              hipStream_t stream)
{
  const float* x        = (const float*)d_in[0];
  const int*   ei0      = (const int*)d_in[1];
  const int*   ei1      = (const int*)d_in[2];
  const float* pre_W0   = (const float*)d_in[3];
  const float* pre_b0   = (const float*)d_in[4];
  const float* pre_g0   = (const float*)d_in[5];
  const float* pre_be0  = (const float*)d_in[6];
  const float* pre_W1   = (const float*)d_in[7];
  const float* pre_b1   = (const float*)d_in[8];
  const float* pre_g1   = (const float*)d_in[9];
  const float* pre_be1  = (const float*)d_in[10];
  const float* gat_Wl   = (const float*)d_in[11];
  const float* gat_Wr   = (const float*)d_in[12];
  const float* gat_att  = (const float*)d_in[13];
  const float* gat_bias = (const float*)d_in[14];
  const float* proj_W   = (const float*)d_in[15];
  const float* proj_b   = (const float*)d_in[16];
  const float* head_W0  = (const float*)d_in[17];
  const float* head_b0  = (const float*)d_in[18];
  const float* head_W1  = (const float*)d_in[19];
  const float* head_b1  = (const float*)d_in[20];
  float* outp = (float*)d_out;

  // ---- workspace arena (all segments 16B-aligned)
  char* ws = (char*)d_ws;
  ushort* xlr_b = (ushort*)ws; ws += (size_t)MP * 1024 * 2;   // fp16 GAT input
  ushort* hb    = (ushort*)ws; ws += (size_t)MP * 256 * 2;
  ushort* outt  = (ushort*)ws; ws += (size_t)MP * 512 * 2;   // gat concat out
  float*  tmp   = (float*)outt;                               // alias: pre-LN f32 buf
  ushort* hbuf  = (ushort*)outt;                              // alias: head0 out
  ushort* W0t      = (ushort*)ws; ws += (size_t)256 * 1024 * 2;
  ushort* W1t      = (ushort*)ws; ws += (size_t)256 * 256 * 2;
  ushort* WcatT    = (ushort*)ws; ws += (size_t)LAYERS * 1024 * 256 * 2;
  ushort* projcatT = (ushort*)ws; ws += (size_t)LAYERS * 256 * 512 * 2;
  ushort* hW0t     = (ushort*)ws; ws += (size_t)256 * 256 * 2;
  ushort* hW1t     = (ushort*)ws; ws += (size_t)128 * 256 * 2;
  int* cnt0  = (int*)ws; ws += (size_t)NPAD * 4;
  int* cnt1  = (int*)ws; ws += (size_t)NPAD * 4;
  int* offs0 = (int*)ws; ws += (size_t)(N_NODES + 4) * 4;
  int* offs1 = (int*)ws; ws += (size_t)(N_NODES + 4) * 4;
  int* cur0  = (int*)ws; ws += (size_t)N_NODES * 4;
  int* cur1  = (int*)ws; ws += (size_t)N_NODES * 4;
  int* bsums = (int*)ws; ws += (size_t)128 * 4;
  int* boffs = (int*)ws; ws += (size_t)128 * 4;
  int* csr0  = (int*)ws; ws += (size_t)EPRIME * 4;
  int* csr1  = (int*)ws; ws += (size_t)EPRIME * 4;

  // ---- CSR build (deterministic via per-bucket sort)
  hipMemsetAsync(cnt0, 0, (size_t)2 * NPAD * 4, stream);   // cnt0+cnt1 contiguous
  const int gE2 = (2 * EPRIME + 255) / 256;
  csr_count2<<<gE2, 256, 0, stream>>>(ei0, ei1, cnt0, cnt1);
  scan_p1<<<2 * SCAN_NBLK, 256, 0, stream>>>(cnt0, cnt1, bsums);
  scan_p2<<<1, 64, 0, stream>>>(bsums, boffs, offs0, offs1);
  scan_p3<<<2 * SCAN_NBLK, 256, 0, stream>>>(cnt0, cnt1, boffs, offs0, cur0, offs1, cur1);
  csr_scatter2<<<gE2, 256, 0, stream>>>(ei0, ei1, cur0, cur1, csr0, csr1);
  csr_sort2<<<(2 * N_NODES + 255) / 256, 256, 0, stream>>>(offs0, csr0, offs1, csr1);

  // ---- weights -> bf16 K-major (single launch)
  wtrans_all<<<WSEG5 / 256, 256, 0, stream>>>(pre_W0, pre_W1, gat_Wl, gat_Wr, proj_W,
                                              head_W0, head_W1,
                                              W0t, W1t, WcatT, projcatT, hW0t, hW1t);

  const dim3 blk(256);
  const int gy = MP / 128;   // 391
  const int gln = (N_NODES * 64 + 255) / 256;   // 12500

  // ---- preprocessor MLP (pre0 reads f32 x directly, casts in staging)
  gemm_k<true><<<dim3(4, gy), blk, 0, stream>>>(x, W0t, 1024, N_NODES, 256,
                                                tmp, nullptr, pre_b0, nullptr, 0, 0);
  ln_relu<<<gln, 256, 0, stream>>>(tmp, hb, pre_g0, pre_be0, N_NODES);
  gemm_k<false><<<dim3(4, gy), blk, 0, stream>>>(hb, W1t, 256, N_NODES, 256,
                                                 tmp, nullptr, pre_b1, nullptr, 0, 0);
  ln_relu<<<gln, 256, 0, stream>>>(tmp, hb, pre_g1, pre_be1, N_NODES);

  // ---- GNN layers
  for (int l = 0; l < LAYERS; l++) {
    gemm_k<false><<<dim3(16, gy), blk, 0, stream>>>(hb, WcatT + (size_t)l * 1024 * 256,
                                                    256, N_NODES, 1024,
                                                    nullptr, xlr_b, nullptr, nullptr, 0, 1);
    gat_edge3<<<2 * gln, 256, 0, stream>>>(
        (const _Float16*)xlr_b, offs0, csr0, offs1, csr1,
        gat_att  + (size_t)l * NTYPES * NHEAD * DHEAD,
        gat_bias + (size_t)l * NTYPES * HID,
        outt, gln);
    gemm_k<false><<<dim3(4, gy), blk, 0, stream>>>(
        outt, projcatT + (size_t)l * 256 * 512, 512, N_NODES, 256,
        nullptr, hb,
        proj_b + (size_t)(l * NTYPES + 0) * HID,
        proj_b + (size_t)(l * NTYPES + 1) * HID, 1, 0);
  }

  // ---- prediction head
  gemm_k<false><<<dim3(4, gy), blk, 0, stream>>>(hb, hW0t, 256, N_NODES, 256,
                                                 nullptr, hbuf, head_b0, nullptr, 1, 0);
  gemm_k<false><<<dim3(1, gy), blk, 0, stream>>>(hbuf, hW1t, 256, N_NODES, OUT_DIM,
                                                 outp, nullptr, head_b1, nullptr, 0, 0);
}

// Round 8
// 805.345 us; speedup vs baseline: 1.0138x; 1.0138x over previous
//
#include <hip/hip_runtime.h>
#include <hip/hip_bf16.h>
#include <math.h>

#define N_NODES 50000
#define MP      50048          // 391 * 128, padded row count
#define E_EDGES 500000
#define EPRIME  (E_EDGES + N_NODES)
#define HID     256
#define PRE_IN  1024
#define OUT_DIM 64
#define NHEAD   4
#define DHEAD   64
#define LAYERS  2
#define NTYPES  2

#define SCAN_NBLK 49                     // ceil(50000/1024)
#define NPAD      (SCAN_NBLK * 1024)     // 50176

typedef __attribute__((ext_vector_type(8))) short short8v;
typedef __attribute__((ext_vector_type(4))) float f32x4;
typedef _Float16 h2v __attribute__((ext_vector_type(2)));
typedef _Float16 h8v __attribute__((ext_vector_type(8)));

__device__ __forceinline__ ushort f2bf(float f) {
  uint u = __float_as_uint(f);
  u += 0x7FFF + ((u >> 16) & 1);          // RNE
  return (ushort)(u >> 16);
}
__device__ __forceinline__ float bf2f(ushort u) {
  return __uint_as_float(((uint)u) << 16);
}

#define SCHEDB __builtin_amdgcn_sched_barrier(0)
#define BARRIER __builtin_amdgcn_s_barrier()

// ------------------------------------------------------------- bf16 MFMA GEMM
// C[M,N] = op(A[M,K] @ Bt[N,K]^T + bias(+bias2)); Bt bf16 K-major (stride lda).
// A: bf16 (AF32=false) or f32 (AF32=true) K-major, stride lda; rows>=M read 0.
// BM=128, BN=64, BK=32; 4 waves, wave-tile 64x32 (acc[4][2], 8 MFMA/K-step).
// Split-K: gridDim.z blocks each cover Klen = lda/gridDim.z; z==0 -> Cf(+bias),
//   z==1 -> Cfz (partial sum, no bias). Caller adds partials downstream.
// T1: bijective XCD-chunked swizzle over the FULL 3D grid.
// AF32 path: raw s_barrier pair -- bottom barrier waits lgkmcnt ONLY, so the
//   next-next tile's A reg-prefetch (issued after the vmcnt-draining top
//   barrier) stays in flight across the whole MFMA phase. Round 6's form
//   drained it immediately (syncthreads = vmcnt(0)); round 7's vmcnt(3) ring
//   capped in-flight loads at 3/wave -- both latency-exposed.
// LDS layout byte = row*64 + (kc ^ ((row>>1)&3))*16 (XOR swizzle both sides).
template<bool AF32>
__global__ __launch_bounds__(256) void gemm_k(
    const void* __restrict__ Ap,
    const ushort* __restrict__ Bt,
    int lda, int Klen, int M, int N,
    float*  __restrict__ Cf,          // f32 out, z==0 (or null)
    float*  __restrict__ Cfz,         // f32 out, z==1 (or null)
    ushort* __restrict__ Cb,          // 16-bit out (or null)
    const float* __restrict__ bias,   // [N] or null (z==0 only)
    const float* __restrict__ bias2,  // [N] or null (z==0 only)
    int do_relu, int out_f16)
{
  __shared__ ushort As[128 * 32];     // 8 KB
  __shared__ ushort Bs[64 * 32];      // 4 KB
  const int tid = threadIdx.x;
  const int l   = tid & 63;
  const int w   = tid >> 6;
  const int wm  = w & 1;              // row half (64 rows)
  const int wn  = w >> 1;             // col quarter (32 cols)

  // ---- T1: bijective XCD-chunked swizzle (m204) over full 3D grid
  const int gx = gridDim.x, gyy = gridDim.y;
  const int nwg  = gx * gyy * gridDim.z;
  const int orig = (blockIdx.z * gyy + blockIdx.y) * gx + blockIdx.x;
  const int qq   = nwg >> 3, rr = nwg & 7;
  const int xcd  = orig & 7;
  const int wgid = ((xcd < rr) ? xcd * (qq + 1) : rr * (qq + 1) + (xcd - rr) * qq)
                   + (orig >> 3);
  const int px = wgid % gx;
  const int py = (wgid / gx) % gyy;
  const int pz = wgid / (gx * gyy);
  const int bm = py * 128;
  const int bn = px * 64;
  const int koff = pz * Klen;
  float* const outF = pz ? Cfz : Cf;

  f32x4 acc[4][2];
#pragma unroll
  for (int m = 0; m < 4; m++)
#pragma unroll
    for (int n = 0; n < 2; n++) acc[m][n] = (f32x4){0.f, 0.f, 0.f, 0.f};

  const int srow  = l >> 2;   // 0..15
  const int sslot = l & 3;    // kc slot
  const int nt    = Klen >> 5;

  // A staging geometry (2 rows per thread)
  int  arow[2], akc[2];
  uint aoff[2];
#pragma unroll
  for (int i = 0; i < 2; i++) {
    arow[i] = w * 32 + i * 16 + srow;
    akc[i]  = sslot ^ ((arow[i] >> 1) & 3);
    aoff[i] = (uint)arow[i] * 64 + (uint)sslot * 16;
  }
  // B staging: one 16B slot per thread, dest = tid*16 (wave-linear)
  const int brow  = tid >> 2;        // 0..63
  const int bslot = tid & 3;
  const int bkc   = bslot ^ ((brow >> 1) & 3);

#define STAGE_B(t)                                                             \
  {                                                                            \
    const ushort* gb = Bt + (size_t)(bn + brow) * lda + koff + ((t) << 5) +    \
                       bkc * 8;                                                \
    __builtin_amdgcn_global_load_lds(                                          \
        (const __attribute__((address_space(1))) uint*)gb,                     \
        (__attribute__((address_space(3))) uint*)((char*)Bs + tid * 16),       \
        16, 0, 0);                                                             \
  }
#define STAGE_A16(t)                                                           \
  _Pragma("unroll")                                                            \
  for (int i = 0; i < 2; i++) {                                                \
    const ushort* ga = (const ushort*)Ap + (size_t)(bm + arow[i]) * lda +      \
                       koff + ((t) << 5) + akc[i] * 8;                         \
    __builtin_amdgcn_global_load_lds(                                          \
        (const __attribute__((address_space(1))) uint*)ga,                     \
        (__attribute__((address_space(3))) uint*)((char*)As + aoff[i]),        \
        16, 0, 0);                                                             \
  }
#define LOAD_A32(t)                                                            \
  _Pragma("unroll")                                                            \
  for (int i = 0; i < 2; i++) {                                                \
    if (bm + arow[i] < M) {                                                    \
      const float* ga = (const float*)Ap + (size_t)(bm + arow[i]) * lda +      \
                        koff + ((t) << 5) + akc[i] * 8;                        \
      pf[i][0] = *reinterpret_cast<const float4*>(ga);                         \
      pf[i][1] = *reinterpret_cast<const float4*>(ga + 4);                     \
    }                                                                          \
  }
#define WRITE_A32()                                                            \
  _Pragma("unroll")                                                            \
  for (int i = 0; i < 2; i++) {                                                \
    short8v s;                                                                 \
    s[0] = (short)f2bf(pf[i][0].x); s[1] = (short)f2bf(pf[i][0].y);            \
    s[2] = (short)f2bf(pf[i][0].z); s[3] = (short)f2bf(pf[i][0].w);            \
    s[4] = (short)f2bf(pf[i][1].x); s[5] = (short)f2bf(pf[i][1].y);            \
    s[6] = (short)f2bf(pf[i][1].z); s[7] = (short)f2bf(pf[i][1].w);            \
    *reinterpret_cast<short8v*>((char*)As + aoff[i]) = s;                      \
  }
#define COMPUTE_TILE()                                                         \
  {                                                                            \
    short8v a[4], b[2];                                                        \
    _Pragma("unroll")                                                          \
    for (int m = 0; m < 4; m++) {                                              \
      const int row = wm * 64 + m * 16 + (l & 15);                             \
      const int kc  = (l >> 4) ^ ((row >> 1) & 3);                             \
      a[m] = *(const short8v*)((const char*)As + row * 64 + kc * 16);          \
    }                                                                          \
    _Pragma("unroll")                                                          \
    for (int n = 0; n < 2; n++) {                                              \
      const int row = wn * 32 + n * 16 + (l & 15);                             \
      const int kc  = (l >> 4) ^ ((row >> 1) & 3);                             \
      b[n] = *(const short8v*)((const char*)Bs + row * 64 + kc * 16);          \
    }                                                                          \
    _Pragma("unroll")                                                          \
    for (int m = 0; m < 4; m++)                                                \
      _Pragma("unroll")                                                        \
      for (int n = 0; n < 2; n++)                                              \
        acc[m][n] = __builtin_amdgcn_mfma_f32_16x16x32_bf16(a[m], b[n],        \
                                                            acc[m][n], 0, 0, 0);\
  }

  if constexpr (AF32) {
    float4 pf[2][2];
#pragma unroll
    for (int i = 0; i < 2; i++) {
      pf[i][0] = make_float4(0.f, 0.f, 0.f, 0.f);
      pf[i][1] = make_float4(0.f, 0.f, 0.f, 0.f);
    }
    LOAD_A32(0);
    STAGE_B(0);
    WRITE_A32();                      // compiler-counted wait on pf only
    asm volatile("s_waitcnt vmcnt(0) lgkmcnt(0)" ::: "memory");
    SCHEDB; BARRIER; SCHEDB;
    if (nt > 1) LOAD_A32(1);          // in flight across MFMA phase
    for (int t = 0; t < nt; t++) {
      COMPUTE_TILE();
      if (t + 1 < nt) {
        asm volatile("s_waitcnt lgkmcnt(0)" ::: "memory");  // LDS reads done
        SCHEDB; BARRIER; SCHEDB;      // pf loads stay in flight (no vmcnt!)
        STAGE_B(t + 1);
        WRITE_A32();                  // waits pf(t+1), leaves B in flight
        asm volatile("s_waitcnt vmcnt(0) lgkmcnt(0)" ::: "memory");
        SCHEDB; BARRIER; SCHEDB;
        if (t + 2 < nt) LOAD_A32(t + 2);
      }
    }
  } else {
    for (int t = 0; t < nt; t++) {
      STAGE_B(t);
      STAGE_A16(t);
      __syncthreads();
      COMPUTE_TILE();
      __syncthreads();
    }
  }

  // epilogue: C/D map col=lane&15, row=(lane>>4)*4+reg
  const int crow0 = bm + wm * 64 + (l >> 4) * 4;
  const int ccol0 = bn + wn * 32 + (l & 15);
#pragma unroll
  for (int m = 0; m < 4; m++) {
#pragma unroll
    for (int j = 0; j < 4; j++) {
      const int grow = crow0 + m * 16 + j;
      if (grow < M) {
#pragma unroll
        for (int n = 0; n < 2; n++) {
          const int gcol = ccol0 + n * 16;
          if (gcol < N) {
            float v = acc[m][n][j];
            if (pz == 0) {
              if (bias)  v += bias[gcol];
              if (bias2) v += bias2[gcol];
            }
            if (do_relu) v = fmaxf(v, 0.f);
            if (outF) outF[(size_t)grow * N + gcol] = v;
            else if (out_f16) {
              _Float16 hv = (_Float16)v;
              Cb[(size_t)grow * N + gcol] = *(ushort*)&hv;
            } else {
              Cb[(size_t)grow * N + gcol] = f2bf(v);
            }
          }
        }
      }
    }
  }
}

// ------------------------------------------------------------ LayerNorm+ReLU
// in (+ optional in2 partial sum) -> bf16 out; one wave per row
__global__ void ln_relu(const float* __restrict__ in, const float* __restrict__ in2,
                        ushort* __restrict__ out,
                        const float* __restrict__ g, const float* __restrict__ be, int n)
{
  int gid = blockIdx.x * blockDim.x + threadIdx.x;
  int row = gid >> 6;
  int lane = threadIdx.x & 63;
  if (row >= n) return;
  float4 v = *reinterpret_cast<const float4*>(in + (size_t)row * HID + lane * 4);
  if (in2) {
    float4 v2 = *reinterpret_cast<const float4*>(in2 + (size_t)row * HID + lane * 4);
    v.x += v2.x; v.y += v2.y; v.z += v2.z; v.w += v2.w;
  }
  float s = v.x + v.y + v.z + v.w;
  float ss = v.x * v.x + v.y * v.y + v.z * v.z + v.w * v.w;
#pragma unroll
  for (int o = 1; o < 64; o <<= 1) { s += __shfl_xor(s, o); ss += __shfl_xor(ss, o); }
  float mu = s * (1.f / 256.f);
  float var = ss * (1.f / 256.f) - mu * mu;
  float inv = rsqrtf(var + 1e-5f);
  float4 gg = *reinterpret_cast<const float4*>(g + lane * 4);
  float4 bb = *reinterpret_cast<const float4*>(be + lane * 4);
  ushort4 o4;
  o4.x = f2bf(fmaxf((v.x - mu) * inv * gg.x + bb.x, 0.f));
  o4.y = f2bf(fmaxf((v.y - mu) * inv * gg.y + bb.y, 0.f));
  o4.z = f2bf(fmaxf((v.z - mu) * inv * gg.z + bb.z, 0.f));
  o4.w = f2bf(fmaxf((v.w - mu) * inv * gg.w + bb.w, 0.f));
  *reinterpret_cast<ushort4*>(out + (size_t)row * HID + lane * 4) = o4;
}

// ------------------------------------------------------------- CSR building
__global__ void csr_count2(const int* __restrict__ ei0, const int* __restrict__ ei1,
                           int* __restrict__ cnt0, int* __restrict__ cnt1)
{
  int e = blockIdx.x * blockDim.x + threadIdx.x;
  if (e >= 2 * EPRIME) return;
  int type = e >= EPRIME;
  int i = type ? e - EPRIME : e;
  const int* ei = type ? ei1 : ei0;
  int* cnt = type ? cnt1 : cnt0;
  int d = (i < E_EDGES) ? ei[E_EDGES + i] : (i - E_EDGES);
  atomicAdd(&cnt[d], 1);
}

// --- hierarchical exclusive scan over cnt0,cnt1 (padded to NPAD with zeros)
__global__ __launch_bounds__(256) void scan_p1(const int* __restrict__ cnt0,
                                               const int* __restrict__ cnt1,
                                               int* __restrict__ bsums)
{
  int type = blockIdx.x >= SCAN_NBLK;
  int blk = type ? blockIdx.x - SCAN_NBLK : blockIdx.x;
  const int* cnt = type ? cnt1 : cnt0;
  int4 v = reinterpret_cast<const int4*>(cnt)[blk * 256 + threadIdx.x];
  int s = v.x + v.y + v.z + v.w;
#pragma unroll
  for (int o = 1; o < 64; o <<= 1) s += __shfl_xor(s, o);
  __shared__ int wt[4];
  if ((threadIdx.x & 63) == 0) wt[threadIdx.x >> 6] = s;
  __syncthreads();
  if (threadIdx.x == 0) bsums[blockIdx.x] = wt[0] + wt[1] + wt[2] + wt[3];
}

__global__ void scan_p2(const int* __restrict__ bsums, int* __restrict__ boffs,
                        int* __restrict__ offs0, int* __restrict__ offs1)
{
  int t = threadIdx.x;
  if (t < 2) {
    int run = 0;
    for (int i = 0; i < SCAN_NBLK; i++) {
      boffs[t * SCAN_NBLK + i] = run;
      run += bsums[t * SCAN_NBLK + i];
    }
  }
  if (t == 2) offs0[N_NODES] = EPRIME;
  if (t == 3) offs1[N_NODES] = EPRIME;
}

__global__ __launch_bounds__(256) void scan_p3(
    const int* __restrict__ cnt0, const int* __restrict__ cnt1,
    const int* __restrict__ boffs,
    int* __restrict__ offs0, int* __restrict__ cur0,
    int* __restrict__ offs1, int* __restrict__ cur1)
{
  int type = blockIdx.x >= SCAN_NBLK;
  int blk = type ? blockIdx.x - SCAN_NBLK : blockIdx.x;
  const int* cnt = type ? cnt1 : cnt0;
  int* offs = type ? offs1 : offs0;
  int* cur  = type ? cur1 : cur0;
  const int tid = threadIdx.x, lane = tid & 63, wv = tid >> 6;
  int4 v = reinterpret_cast<const int4*>(cnt)[blk * 256 + tid];
  int e1 = v.x, e2 = e1 + v.y, e3 = e2 + v.z, T = e3 + v.w;
  int incl = T;
#pragma unroll
  for (int o = 1; o < 64; o <<= 1) {
    int nb = __shfl_up(incl, o);
    if (lane >= o) incl += nb;
  }
  __shared__ int wt[4];
  if (lane == 63) wt[wv] = incl;
  __syncthreads();
  int wexcl = 0;
  for (int i = 0; i < wv; i++) wexcl += wt[i];
  int base = boffs[blockIdx.x] + wexcl + (incl - T);
  int idx = blk * 1024 + tid * 4;
  int4 o4 = make_int4(base, base + e1, base + e2, base + e3);
  if (idx + 3 < N_NODES) {
    reinterpret_cast<int4*>(offs)[idx >> 2] = o4;
    reinterpret_cast<int4*>(cur)[idx >> 2] = o4;
  } else {
    if (idx + 0 < N_NODES) { offs[idx + 0] = o4.x; cur[idx + 0] = o4.x; }
    if (idx + 1 < N_NODES) { offs[idx + 1] = o4.y; cur[idx + 1] = o4.y; }
    if (idx + 2 < N_NODES) { offs[idx + 2] = o4.z; cur[idx + 2] = o4.z; }
    if (idx + 3 < N_NODES) { offs[idx + 3] = o4.w; cur[idx + 3] = o4.w; }
  }
}

__global__ void csr_scatter2(const int* __restrict__ ei0, const int* __restrict__ ei1,
                             int* __restrict__ cur0, int* __restrict__ cur1,
                             int* __restrict__ csr0, int* __restrict__ csr1)
{
  int e = blockIdx.x * blockDim.x + threadIdx.x;
  if (e >= 2 * EPRIME) return;
  int type = e >= EPRIME;
  int i = type ? e - EPRIME : e;
  const int* ei = type ? ei1 : ei0;
  int* cur = type ? cur1 : cur0;
  int* csr = type ? csr1 : csr0;
  int d = (i < E_EDGES) ? ei[E_EDGES + i] : (i - E_EDGES);
  int s = (i < E_EDGES) ? ei[i] : (i - E_EDGES);
  int pos = atomicAdd(&cur[d], 1);
  csr[pos] = s;
}

__global__ void csr_sort2(const int* __restrict__ offs0, int* __restrict__ csr0,
                          const int* __restrict__ offs1, int* __restrict__ csr1)
{
  int d = blockIdx.x * blockDim.x + threadIdx.x;
  if (d >= 2 * N_NODES) return;
  int type = d >= N_NODES;
  int i = type ? d - N_NODES : d;
  const int* offs = type ? offs1 : offs0;
  int* csr = type ? csr1 : csr0;
  int b = offs[i], e = offs[i + 1];
  for (int p = b + 1; p < e; p++) {
    int v = csr[p];
    int j = p - 1;
    while (j >= b && csr[j] > v) { csr[j + 1] = csr[j]; j--; }
    csr[j + 1] = v;
  }
}

// --------------------------------- all weight transposes/casts in one kernel
#define WSEG0 262144              // W0t   [256][1024]
#define WSEG1 (WSEG0 + 65536)     // W1t   [256][256]
#define WSEG2 (WSEG1 + 524288)    // WcatT [L][1024][256]
#define WSEG3 (WSEG2 + 262144)    // projcatT [L][256][512]
#define WSEG4 (WSEG3 + 65536)     // hW0t  [256][256]
#define WSEG5 (WSEG4 + 32768)     // hW1t  [128][256]
__global__ void wtrans_all(const float* __restrict__ pre_W0, const float* __restrict__ pre_W1,
                           const float* __restrict__ Wl, const float* __restrict__ Wr,
                           const float* __restrict__ proj_W,
                           const float* __restrict__ head_W0, const float* __restrict__ head_W1,
                           ushort* __restrict__ W0t, ushort* __restrict__ W1t,
                           ushort* __restrict__ WcatT, ushort* __restrict__ projcatT,
                           ushort* __restrict__ hW0t, ushort* __restrict__ hW1t)
{
  int i = blockIdx.x * blockDim.x + threadIdx.x;
  if (i < WSEG0) {
    int nrow = i >> 10, k = i & 1023;
    W0t[i] = f2bf(pre_W0[(size_t)k * 256 + nrow]);
  } else if (i < WSEG1) {
    int j = i - WSEG0;
    int nrow = j >> 8, k = j & 255;
    W1t[j] = f2bf(pre_W1[(size_t)k * 256 + nrow]);
  } else if (i < WSEG2) {
    int j = i - WSEG1;
    int l = j >> 18;
    int rem = j & 262143;
    int c = rem >> 8, k = rem & 255;
    int t = c >> 9, half = (c >> 8) & 1, cc = c & 255;
    const float* W = half ? Wr : Wl;
    WcatT[j] = f2bf(W[(((size_t)l * NTYPES + t) * 256 + k) * 256 + cc]);
  } else if (i < WSEG3) {
    int j = i - WSEG2;
    int l = j >> 17;
    int rem = j & 131071;
    int n = rem >> 9, k = rem & 511;
    int t = k >> 8, kk = k & 255;
    projcatT[j] = f2bf(proj_W[(((size_t)l * NTYPES + t) * 256 + kk) * 256 + n]);
  } else if (i < WSEG4) {
    int j = i - WSEG3;
    int nrow = j >> 8, k = j & 255;
    hW0t[j] = f2bf(head_W0[(size_t)k * 256 + nrow]);
  } else if (i < WSEG5) {
    int j = i - WSEG4;
    int nrow = j >> 8, k = j & 255;
    hW1t[j] = (nrow < OUT_DIM) ? f2bf(head_W1[(size_t)k * OUT_DIM + nrow]) : (ushort)0;
  }
}

// --------------------------------------------------------- DPP 8-lane reduce
__device__ __forceinline__ float dpp8_sum(float p) {
  p += __int_as_float(__builtin_amdgcn_update_dpp(0, __float_as_int(p), 0xB1, 0xF, 0xF, true));
  p += __int_as_float(__builtin_amdgcn_update_dpp(0, __float_as_int(p), 0x4E, 0xF, 0xF, true));
  p += __int_as_float(__builtin_amdgcn_update_dpp(0, __float_as_int(p), 0x141, 0xF, 0xF, true));
  return p;
}

__device__ __forceinline__ h8v leaky8(h8v x) {
  const _Float16 c = (_Float16)0.2f;
  h8v y = x * c;
#if __has_builtin(__builtin_elementwise_max)
  return __builtin_elementwise_max(x, y);
#else
  h8v r;
#pragma unroll
  for (int i = 0; i < 8; i++) r[i] = x[i] > y[i] ? x[i] : y[i];
  return r;
#endif
}

__device__ __forceinline__ float dot8(h8v e, const h2v* a) {
  h2v e0 = {e[0], e[1]}, e1 = {e[2], e[3]}, e2 = {e[4], e[5]}, e3 = {e[6], e[7]};
#if __has_builtin(__builtin_amdgcn_fdot2)
  float s = __builtin_amdgcn_fdot2(e0, a[0], 0.f, false);
  s = __builtin_amdgcn_fdot2(e1, a[1], s, false);
  s = __builtin_amdgcn_fdot2(e2, a[2], s, false);
  s = __builtin_amdgcn_fdot2(e3, a[3], s, false);
  return s;
#else
  float s = 0.f;
#pragma unroll
  for (int i = 0; i < 8; i++) s += (float)e[i] * (float)a[i >> 1][i & 1];
  return s;
#endif
}

// ---------------------------------------------- GATv2: dst-centric online SM
__global__ __launch_bounds__(256) void gat_edge3(
    const _Float16* __restrict__ xlr,   // [MP,1024] fp16
    const int* __restrict__ offs0, const int* __restrict__ csr0,
    const int* __restrict__ offs1, const int* __restrict__ csr1,
    const float* __restrict__ att,      // [2*256] layer base
    const float* __restrict__ bias,     // [2*256] layer base
    ushort* __restrict__ out, int nblk_per_type)
{
  const int type = blockIdx.x >= nblk_per_type;
  const int bid = type ? blockIdx.x - nblk_per_type : blockIdx.x;
  const int wid = (bid * 256 + threadIdx.x) >> 6;
  if (wid >= N_NODES) return;
  const int lane = threadIdx.x & 63;
  const int half = lane >> 5, li = lane & 31;
  const int* offs = type ? offs1 : offs0;
  const int* csr  = type ? csr1 : csr0;
  const int xl_col = type ? 512 : 0;

  const float* ap = att + type * 256 + li * 8;
  h2v a[4];
#pragma unroll
  for (int i = 0; i < 4; i++) {
    a[i][0] = (_Float16)ap[2 * i];
    a[i][1] = (_Float16)ap[2 * i + 1];
  }
  const h8v xr = *reinterpret_cast<const h8v*>(xlr + (size_t)wid * 1024 + xl_col + 256 + li * 8);

  const int beg = offs[wid], end = offs[wid + 1];
  const float L2E = 1.44269504f;
  float m = -1e30f, den = 0.f;
  float acc[8];
#pragma unroll
  for (int i = 0; i < 8; i++) acc[i] = 0.f;

  const int ng = (end - beg + 3) >> 2;
  for (int g = 0; g < ng; g++) {
    const int j0 = beg + 4 * g + half;
    const int j1 = j0 + 2;
    const bool v0 = j0 < end, v1 = j1 < end;
    const int s0 = csr[v0 ? j0 : beg];
    const int s1 = csr[v1 ? j1 : beg];
    const h8v hs0 = *reinterpret_cast<const h8v*>(xlr + (size_t)s0 * 1024 + xl_col + li * 8);
    const h8v hs1 = *reinterpret_cast<const h8v*>(xlr + (size_t)s1 * 1024 + xl_col + li * 8);
    float p0 = dpp8_sum(dot8(leaky8(hs0 + xr), a));
    float p1 = dpp8_sum(dot8(leaky8(hs1 + xr), a));
    if (!v0) p0 = -INFINITY;
    if (!v1) p1 = -INFINITY;
    const float pm = fmaxf(p0, p1);
    if (__any(pm > m + 4.f)) {           // defer-max rescale (rare)
      const float nm = fmaxf(m, pm);
      const float so = exp2f((m - nm) * L2E);
      den *= so;
#pragma unroll
      for (int i = 0; i < 8; i++) acc[i] *= so;
      m = nm;
    }
    const float w0 = exp2f((p0 - m) * L2E);
    const float w1 = exp2f((p1 - m) * L2E);
    den += w0 + w1;
#pragma unroll
    for (int i = 0; i < 8; i++) {
      acc[i] = fmaf((float)hs0[i], w0, acc[i]);
      acc[i] = fmaf((float)hs1[i], w1, acc[i]);
    }
  }

  const float mo  = __shfl_xor(m, 32);
  const float dno = __shfl_xor(den, 32);
  const float ms = fmaxf(m, mo);
  const float fa = exp2f((m - ms) * L2E);
  const float fb = exp2f((mo - ms) * L2E);
  const float r = 1.f / (den * fa + dno * fb + 1e-16f);
  float of[8];
#pragma unroll
  for (int i = 0; i < 8; i++)
    of[i] = (acc[i] * fa + __shfl_xor(acc[i], 32) * fb) * r;

  if (half == 0) {
    const float* bp = bias + type * 256 + li * 8;
    uint4 o;
    uint pk[4];
#pragma unroll
    for (int i = 0; i < 4; i++) {
      const uint lo = f2bf(of[2 * i] + bp[2 * i]);
      const uint hi = f2bf(of[2 * i + 1] + bp[2 * i + 1]);
      pk[i] = lo | (hi << 16);
    }
    o.x = pk[0]; o.y = pk[1]; o.z = pk[2]; o.w = pk[3];
    *reinterpret_cast<uint4*>(out + (size_t)wid * 512 + type * 256 + li * 8) = o;
  }
}

// ----------------------------------------------------------------- launcher
extern "C" void kernel_launch(void* const* d_in, const int* in_sizes, int n_in,
                              void* d_out, int out_size, void* d_ws, size_t ws_size,
                              hipStream_t stream)
{
  const float* x        = (const float*)d_in[0];
  const int*   ei0      = (const int*)d_in[1];
  const int*   ei1      = (const int*)d_in[2];
  const float* pre_W0   = (const float*)d_in[3];
  const float* pre_b0   = (const float*)d_in[4];
  const float* pre_g0   = (const float*)d_in[5];
  const float* pre_be0  = (const float*)d_in[6];
  const float* pre_W1   = (const float*)d_in[7];
  const float* pre_b1   = (const float*)d_in[8];
  const float* pre_g1   = (const float*)d_in[9];
  const float* pre_be1  = (const float*)d_in[10];
  const float* gat_Wl   = (const float*)d_in[11];
  const float* gat_Wr   = (const float*)d_in[12];
  const float* gat_att  = (const float*)d_in[13];
  const float* gat_bias = (const float*)d_in[14];
  const float* proj_W   = (const float*)d_in[15];
  const float* proj_b   = (const float*)d_in[16];
  const float* head_W0  = (const float*)d_in[17];
  const float* head_b0  = (const float*)d_in[18];
  const float* head_W1  = (const float*)d_in[19];
  const float* head_b1  = (const float*)d_in[20];
  float* outp = (float*)d_out;

  // ---- workspace arena (all segments 16B-aligned)
  char* ws = (char*)d_ws;
  ushort* xlr_b = (ushort*)ws; ws += (size_t)MP * 1024 * 2;   // fp16 GAT input
  ushort* hb    = (ushort*)ws; ws += (size_t)MP * 256 * 2;
  ushort* outt  = (ushort*)ws; ws += (size_t)MP * 512 * 2;   // gat concat out
  float*  tmp   = (float*)outt;                               // alias: pre-LN f32 buf
  float*  tmp2  = (float*)xlr_b;                              // alias: split-K partial
  ushort* hbuf  = (ushort*)outt;                              // alias: head0 out
  ushort* W0t      = (ushort*)ws; ws += (size_t)256 * 1024 * 2;
  ushort* W1t      = (ushort*)ws; ws += (size_t)256 * 256 * 2;
  ushort* WcatT    = (ushort*)ws; ws += (size_t)LAYERS * 1024 * 256 * 2;
  ushort* projcatT = (ushort*)ws; ws += (size_t)LAYERS * 256 * 512 * 2;
  ushort* hW0t     = (ushort*)ws; ws += (size_t)256 * 256 * 2;
  ushort* hW1t     = (ushort*)ws; ws += (size_t)128 * 256 * 2;
  int* cnt0  = (int*)ws; ws += (size_t)NPAD * 4;
  int* cnt1  = (int*)ws; ws += (size_t)NPAD * 4;
  int* offs0 = (int*)ws; ws += (size_t)(N_NODES + 4) * 4;
  int* offs1 = (int*)ws; ws += (size_t)(N_NODES + 4) * 4;
  int* cur0  = (int*)ws; ws += (size_t)N_NODES * 4;
  int* cur1  = (int*)ws; ws += (size_t)N_NODES * 4;
  int* bsums = (int*)ws; ws += (size_t)128 * 4;
  int* boffs = (int*)ws; ws += (size_t)128 * 4;
  int* csr0  = (int*)ws; ws += (size_t)EPRIME * 4;
  int* csr1  = (int*)ws; ws += (size_t)EPRIME * 4;

  // ---- CSR build (deterministic via per-bucket sort)
  hipMemsetAsync(cnt0, 0, (size_t)2 * NPAD * 4, stream);   // cnt0+cnt1 contiguous
  const int gE2 = (2 * EPRIME + 255) / 256;
  csr_count2<<<gE2, 256, 0, stream>>>(ei0, ei1, cnt0, cnt1);
  scan_p1<<<2 * SCAN_NBLK, 256, 0, stream>>>(cnt0, cnt1, bsums);
  scan_p2<<<1, 64, 0, stream>>>(bsums, boffs, offs0, offs1);
  scan_p3<<<2 * SCAN_NBLK, 256, 0, stream>>>(cnt0, cnt1, boffs, offs0, cur0, offs1, cur1);
  csr_scatter2<<<gE2, 256, 0, stream>>>(ei0, ei1, cur0, cur1, csr0, csr1);
  csr_sort2<<<(2 * N_NODES + 255) / 256, 256, 0, stream>>>(offs0, csr0, offs1, csr1);

  // ---- weights -> bf16 K-major (single launch)
  wtrans_all<<<WSEG5 / 256, 256, 0, stream>>>(pre_W0, pre_W1, gat_Wl, gat_Wr, proj_W,
                                              head_W0, head_W1,
                                              W0t, W1t, WcatT, projcatT, hW0t, hW1t);

  const dim3 blk(256);
  const int gy = MP / 128;   // 391
  const int gln = (N_NODES * 64 + 255) / 256;   // 12500

  // ---- preprocessor MLP (split-K=2: partial sums to tmp/tmp2, summed in ln)
  gemm_k<true><<<dim3(4, gy, 2), blk, 0, stream>>>(x, W0t, 1024, 512, N_NODES, 256,
                                                   tmp, tmp2, nullptr, pre_b0, nullptr, 0, 0);
  ln_relu<<<gln, 256, 0, stream>>>(tmp, tmp2, hb, pre_g0, pre_be0, N_NODES);
  gemm_k<false><<<dim3(4, gy, 2), blk, 0, stream>>>(hb, W1t, 256, 128, N_NODES, 256,
                                                    tmp, tmp2, nullptr, pre_b1, nullptr, 0, 0);
  ln_relu<<<gln, 256, 0, stream>>>(tmp, tmp2, hb, pre_g1, pre_be1, N_NODES);

  // ---- GNN layers
  for (int l = 0; l < LAYERS; l++) {
    gemm_k<false><<<dim3(16, gy), blk, 0, stream>>>(hb, WcatT + (size_t)l * 1024 * 256,
                                                    256, 256, N_NODES, 1024,
                                                    nullptr, nullptr, xlr_b,
                                                    nullptr, nullptr, 0, 1);
    gat_edge3<<<2 * gln, 256, 0, stream>>>(
        (const _Float16*)xlr_b, offs0, csr0, offs1, csr1,
        gat_att  + (size_t)l * NTYPES * NHEAD * DHEAD,
        gat_bias + (size_t)l * NTYPES * HID,
        outt, gln);
    gemm_k<false><<<dim3(4, gy), blk, 0, stream>>>(
        outt, projcatT + (size_t)l * 256 * 512, 512, 512, N_NODES, 256,
        nullptr, nullptr, hb,
        proj_b + (size_t)(l * NTYPES + 0) * HID,
        proj_b + (size_t)(l * NTYPES + 1) * HID, 1, 0);
  }

  // ---- prediction head
  gemm_k<false><<<dim3(4, gy), blk, 0, stream>>>(hb, hW0t, 256, 256, N_NODES, 256,
                                                 nullptr, nullptr, hbuf,
                                                 head_b0, nullptr, 1, 0);
  gemm_k<false><<<dim3(1, gy), blk, 0, stream>>>(hbuf, hW1t, 256, 256, N_NODES, OUT_DIM,
                                                 outp, nullptr, nullptr,
                                                 head_b1, nullptr, 0, 0);
}

// Round 9
// 775.712 us; speedup vs baseline: 1.0525x; 1.0382x over previous
//
#include <hip/hip_runtime.h>
#include <hip/hip_bf16.h>
#include <math.h>

#define N_NODES 50000
#define MP      50048          // 391 * 128, padded row count
#define E_EDGES 500000
#define EPRIME  (E_EDGES + N_NODES)
#define HID     256
#define PRE_IN  1024
#define OUT_DIM 64
#define NHEAD   4
#define DHEAD   64
#define LAYERS  2
#define NTYPES  2

#define SCAN_NBLK 49                     // ceil(50000/1024)
#define NPAD      (SCAN_NBLK * 1024)     // 50176

typedef __attribute__((ext_vector_type(8))) short short8v;
typedef __attribute__((ext_vector_type(4))) float f32x4;
typedef _Float16 h2v __attribute__((ext_vector_type(2)));
typedef _Float16 h8v __attribute__((ext_vector_type(8)));

__device__ __forceinline__ ushort f2bf(float f) {
  uint u = __float_as_uint(f);
  u += 0x7FFF + ((u >> 16) & 1);          // RNE
  return (ushort)(u >> 16);
}
__device__ __forceinline__ float bf2f(ushort u) {
  return __uint_as_float(((uint)u) << 16);
}

// ------------------------------------------------------------- bf16 MFMA GEMM
// C[M,N] = op(A[M,K] @ Bt[N,K]^T + bias(+bias2)); A,Bt bf16 K-major, rows padded.
// BM=128, BN=64, BK=32; 4 waves, wave-tile 64x32 (acc[4][2], 8 MFMA/K-step).
// R6-proven form: global_load_lds staging + __syncthreads 2-barrier loop.
// T1: bijective XCD-chunked blockIdx swizzle (m204) -- same-stripe col tiles
//     on one XCD L2 (R6: FETCH 401->105 MB).
// Pre0 now reads a PRE-CAST bf16 xb (see prep_all): the f32 x column-walk was
//   DRAM-page-hostile (R4-R8: ~145-190us regardless of schedule); the cast
//   streams x once at full BW and the GEMM re-reads bf16 from L3.
// LDS layout byte = row*64 + (kc ^ ((row>>1)&3))*16 (XOR swizzle both sides).
__global__ __launch_bounds__(256) void gemm_k(
    const ushort* __restrict__ A,
    const ushort* __restrict__ Bt,
    int K, int M, int N,
    float*  __restrict__ Cf,          // f32 out (or null)
    ushort* __restrict__ Cb,          // 16-bit out (or null)
    const float* __restrict__ bias,   // [N] or null
    const float* __restrict__ bias2,  // [N] or null (added too)
    int do_relu, int out_f16)         // out_f16: Cb holds fp16 instead of bf16
{
  __shared__ ushort As[128 * 32];     // 8 KB
  __shared__ ushort Bs[64 * 32];      // 4 KB
  const int tid = threadIdx.x;
  const int l   = tid & 63;
  const int w   = tid >> 6;
  const int wm  = w & 1;              // row half (64 rows)
  const int wn  = w >> 1;             // col quarter (32 cols)

  // ---- T1: bijective XCD-chunked swizzle (m204)
  const int nwg  = gridDim.x * gridDim.y;
  const int orig = blockIdx.y * gridDim.x + blockIdx.x;
  const int qq   = nwg >> 3, rr = nwg & 7;
  const int xcd  = orig & 7;
  const int wgid = ((xcd < rr) ? xcd * (qq + 1) : rr * (qq + 1) + (xcd - rr) * qq)
                   + (orig >> 3);
  const int bm = (wgid / gridDim.x) * 128;
  const int bn = (wgid % gridDim.x) * 64;

  f32x4 acc[4][2];
#pragma unroll
  for (int m = 0; m < 4; m++)
#pragma unroll
    for (int n = 0; n < 2; n++) acc[m][n] = (f32x4){0.f, 0.f, 0.f, 0.f};

  const int srow  = l >> 2;   // 0..15
  const int sslot = l & 3;    // kc slot
  const int nt    = K >> 5;

  // A staging geometry (2 rows per thread)
  int  arow[2], akc[2];
  uint aoff[2];
#pragma unroll
  for (int i = 0; i < 2; i++) {
    arow[i] = w * 32 + i * 16 + srow;
    akc[i]  = sslot ^ ((arow[i] >> 1) & 3);
    aoff[i] = (uint)arow[i] * 64 + (uint)sslot * 16;
  }
  // B staging: one 16B slot per thread, dest = tid*16 (wave-linear)
  const int brow  = tid >> 2;        // 0..63
  const int bslot = tid & 3;
  const int bkc   = bslot ^ ((brow >> 1) & 3);

  for (int t = 0; t < nt; t++) {
    const int k0 = t << 5;
    {
      const ushort* gb = Bt + (size_t)(bn + brow) * K + k0 + bkc * 8;
      __builtin_amdgcn_global_load_lds(
          (const __attribute__((address_space(1))) uint*)gb,
          (__attribute__((address_space(3))) uint*)((char*)Bs + tid * 16), 16, 0, 0);
    }
#pragma unroll
    for (int i = 0; i < 2; i++) {
      const ushort* ga = A + (size_t)(bm + arow[i]) * K + k0 + akc[i] * 8;
      __builtin_amdgcn_global_load_lds(
          (const __attribute__((address_space(1))) uint*)ga,
          (__attribute__((address_space(3))) uint*)((char*)As + aoff[i]), 16, 0, 0);
    }
    __syncthreads();

    short8v a[4], b[2];
#pragma unroll
    for (int m = 0; m < 4; m++) {
      const int row = wm * 64 + m * 16 + (l & 15);
      const int kc  = (l >> 4) ^ ((row >> 1) & 3);
      a[m] = *(const short8v*)((const char*)As + row * 64 + kc * 16);
    }
#pragma unroll
    for (int n = 0; n < 2; n++) {
      const int row = wn * 32 + n * 16 + (l & 15);
      const int kc  = (l >> 4) ^ ((row >> 1) & 3);
      b[n] = *(const short8v*)((const char*)Bs + row * 64 + kc * 16);
    }
#pragma unroll
    for (int m = 0; m < 4; m++)
#pragma unroll
      for (int n = 0; n < 2; n++)
        acc[m][n] = __builtin_amdgcn_mfma_f32_16x16x32_bf16(a[m], b[n], acc[m][n], 0, 0, 0);
    __syncthreads();
  }

  // epilogue: C/D map col=lane&15, row=(lane>>4)*4+reg
  const int crow0 = bm + wm * 64 + (l >> 4) * 4;
  const int ccol0 = bn + wn * 32 + (l & 15);
#pragma unroll
  for (int m = 0; m < 4; m++) {
#pragma unroll
    for (int j = 0; j < 4; j++) {
      const int grow = crow0 + m * 16 + j;
      if (grow < M) {
#pragma unroll
        for (int n = 0; n < 2; n++) {
          const int gcol = ccol0 + n * 16;
          if (gcol < N) {
            float v = acc[m][n][j];
            if (bias)  v += bias[gcol];
            if (bias2) v += bias2[gcol];
            if (do_relu) v = fmaxf(v, 0.f);
            if (Cf) Cf[(size_t)grow * N + gcol] = v;
            else if (out_f16) {
              _Float16 hv = (_Float16)v;
              Cb[(size_t)grow * N + gcol] = *(ushort*)&hv;
            } else {
              Cb[(size_t)grow * N + gcol] = f2bf(v);
            }
          }
        }
      }
    }
  }
}

// ------------------------------------------------------------ LayerNorm+ReLU
__global__ void ln_relu(const float* __restrict__ in, ushort* __restrict__ out,
                        const float* __restrict__ g, const float* __restrict__ be, int n)
{
  int gid = blockIdx.x * blockDim.x + threadIdx.x;
  int row = gid >> 6;
  int lane = threadIdx.x & 63;
  if (row >= n) return;
  float4 v = *reinterpret_cast<const float4*>(in + (size_t)row * HID + lane * 4);
  float s = v.x + v.y + v.z + v.w;
  float ss = v.x * v.x + v.y * v.y + v.z * v.z + v.w * v.w;
#pragma unroll
  for (int o = 1; o < 64; o <<= 1) { s += __shfl_xor(s, o); ss += __shfl_xor(ss, o); }
  float mu = s * (1.f / 256.f);
  float var = ss * (1.f / 256.f) - mu * mu;
  float inv = rsqrtf(var + 1e-5f);
  float4 gg = *reinterpret_cast<const float4*>(g + lane * 4);
  float4 bb = *reinterpret_cast<const float4*>(be + lane * 4);
  ushort4 o4;
  o4.x = f2bf(fmaxf((v.x - mu) * inv * gg.x + bb.x, 0.f));
  o4.y = f2bf(fmaxf((v.y - mu) * inv * gg.y + bb.y, 0.f));
  o4.z = f2bf(fmaxf((v.z - mu) * inv * gg.z + bb.z, 0.f));
  o4.w = f2bf(fmaxf((v.w - mu) * inv * gg.w + bb.w, 0.f));
  *reinterpret_cast<ushort4*>(out + (size_t)row * HID + lane * 4) = o4;
}

// -------------------- fused prep: wtrans + csr_count + x cast (one launch)
// Region A (blocks [0, NWT)): weight transpose/cast to bf16 K-major.
// Region B (blocks [NWT, NWT+NCNT)): csr in-degree count (atomic).
// Region C (rest, NCAST blocks): x f32 -> bf16 streaming cast (row-linear,
//   DRAM-friendly; makes the pre0 GEMM's A-reads L3-resident bf16).
#define WSEG0 262144              // W0t   [256][1024]
#define WSEG1 (WSEG0 + 65536)     // W1t   [256][256]
#define WSEG2 (WSEG1 + 524288)    // WcatT [L][1024][256]
#define WSEG3 (WSEG2 + 262144)    // projcatT [L][256][512]
#define WSEG4 (WSEG3 + 65536)     // hW0t  [256][256]
#define WSEG5 (WSEG4 + 32768)     // hW1t  [128][256]
#define NWT   (WSEG5 / 256)       // 4736
#define NCNT  ((2 * EPRIME + 255) / 256)   // 4297
#define NCAST 4096
#define CAST_UNITS (N_NODES * 1024 / 8)    // 6.4M short8 units

__global__ void prep_all(const float* __restrict__ pre_W0, const float* __restrict__ pre_W1,
                         const float* __restrict__ Wl, const float* __restrict__ Wr,
                         const float* __restrict__ proj_W,
                         const float* __restrict__ head_W0, const float* __restrict__ head_W1,
                         ushort* __restrict__ W0t, ushort* __restrict__ W1t,
                         ushort* __restrict__ WcatT, ushort* __restrict__ projcatT,
                         ushort* __restrict__ hW0t, ushort* __restrict__ hW1t,
                         const int* __restrict__ ei0, const int* __restrict__ ei1,
                         int* __restrict__ cnt0, int* __restrict__ cnt1,
                         const float* __restrict__ x, ushort* __restrict__ xb)
{
  const int bid = blockIdx.x;
  if (bid < NWT) {
    int i = bid * 256 + threadIdx.x;
    if (i < WSEG0) {
      int nrow = i >> 10, k = i & 1023;
      W0t[i] = f2bf(pre_W0[(size_t)k * 256 + nrow]);
    } else if (i < WSEG1) {
      int j = i - WSEG0;
      int nrow = j >> 8, k = j & 255;
      W1t[j] = f2bf(pre_W1[(size_t)k * 256 + nrow]);
    } else if (i < WSEG2) {
      int j = i - WSEG1;
      int l = j >> 18;
      int rem = j & 262143;
      int c = rem >> 8, k = rem & 255;
      int t = c >> 9, half = (c >> 8) & 1, cc = c & 255;
      const float* W = half ? Wr : Wl;
      WcatT[j] = f2bf(W[(((size_t)l * NTYPES + t) * 256 + k) * 256 + cc]);
    } else if (i < WSEG3) {
      int j = i - WSEG2;
      int l = j >> 17;
      int rem = j & 131071;
      int n = rem >> 9, k = rem & 511;
      int t = k >> 8, kk = k & 255;
      projcatT[j] = f2bf(proj_W[(((size_t)l * NTYPES + t) * 256 + kk) * 256 + n]);
    } else if (i < WSEG4) {
      int j = i - WSEG3;
      int nrow = j >> 8, k = j & 255;
      hW0t[j] = f2bf(head_W0[(size_t)k * 256 + nrow]);
    } else if (i < WSEG5) {
      int j = i - WSEG4;
      int nrow = j >> 8, k = j & 255;
      hW1t[j] = (nrow < OUT_DIM) ? f2bf(head_W1[(size_t)k * OUT_DIM + nrow]) : (ushort)0;
    }
  } else if (bid < NWT + NCNT) {
    int e = (bid - NWT) * 256 + threadIdx.x;
    if (e < 2 * EPRIME) {
      int type = e >= EPRIME;
      int i = type ? e - EPRIME : e;
      const int* ei = type ? ei1 : ei0;
      int* cnt = type ? cnt1 : cnt0;
      int d = (i < E_EDGES) ? ei[E_EDGES + i] : (i - E_EDGES);
      atomicAdd(&cnt[d], 1);
    }
  } else {
    // streaming cast, grid-stride
    const float4* xf = (const float4*)x;
    short8v* xo = (short8v*)xb;
    for (size_t i = (size_t)(bid - NWT - NCNT) * 256 + threadIdx.x;
         i < (size_t)CAST_UNITS; i += (size_t)NCAST * 256) {
      float4 v0 = xf[2 * i];
      float4 v1 = xf[2 * i + 1];
      short8v s;
      s[0] = (short)f2bf(v0.x); s[1] = (short)f2bf(v0.y);
      s[2] = (short)f2bf(v0.z); s[3] = (short)f2bf(v0.w);
      s[4] = (short)f2bf(v1.x); s[5] = (short)f2bf(v1.y);
      s[6] = (short)f2bf(v1.z); s[7] = (short)f2bf(v1.w);
      xo[i] = s;
    }
  }
}

// --- hierarchical exclusive scan over cnt0,cnt1 (padded to NPAD with zeros)
__global__ __launch_bounds__(256) void scan_p1(const int* __restrict__ cnt0,
                                               const int* __restrict__ cnt1,
                                               int* __restrict__ bsums)
{
  int type = blockIdx.x >= SCAN_NBLK;
  int blk = type ? blockIdx.x - SCAN_NBLK : blockIdx.x;
  const int* cnt = type ? cnt1 : cnt0;
  int4 v = reinterpret_cast<const int4*>(cnt)[blk * 256 + threadIdx.x];
  int s = v.x + v.y + v.z + v.w;
#pragma unroll
  for (int o = 1; o < 64; o <<= 1) s += __shfl_xor(s, o);
  __shared__ int wt[4];
  if ((threadIdx.x & 63) == 0) wt[threadIdx.x >> 6] = s;
  __syncthreads();
  if (threadIdx.x == 0) bsums[blockIdx.x] = wt[0] + wt[1] + wt[2] + wt[3];
}

__global__ void scan_p2(const int* __restrict__ bsums, int* __restrict__ boffs,
                        int* __restrict__ offs0, int* __restrict__ offs1)
{
  int t = threadIdx.x;
  if (t < 2) {
    int run = 0;
    for (int i = 0; i < SCAN_NBLK; i++) {
      boffs[t * SCAN_NBLK + i] = run;
      run += bsums[t * SCAN_NBLK + i];
    }
  }
  if (t == 2) offs0[N_NODES] = EPRIME;
  if (t == 3) offs1[N_NODES] = EPRIME;
}

__global__ __launch_bounds__(256) void scan_p3(
    const int* __restrict__ cnt0, const int* __restrict__ cnt1,
    const int* __restrict__ boffs,
    int* __restrict__ offs0, int* __restrict__ cur0,
    int* __restrict__ offs1, int* __restrict__ cur1)
{
  int type = blockIdx.x >= SCAN_NBLK;
  int blk = type ? blockIdx.x - SCAN_NBLK : blockIdx.x;
  const int* cnt = type ? cnt1 : cnt0;
  int* offs = type ? offs1 : offs0;
  int* cur  = type ? cur1 : cur0;
  const int tid = threadIdx.x, lane = tid & 63, wv = tid >> 6;
  int4 v = reinterpret_cast<const int4*>(cnt)[blk * 256 + tid];
  int e1 = v.x, e2 = e1 + v.y, e3 = e2 + v.z, T = e3 + v.w;
  int incl = T;
#pragma unroll
  for (int o = 1; o < 64; o <<= 1) {
    int nb = __shfl_up(incl, o);
    if (lane >= o) incl += nb;
  }
  __shared__ int wt[4];
  if (lane == 63) wt[wv] = incl;
  __syncthreads();
  int wexcl = 0;
  for (int i = 0; i < wv; i++) wexcl += wt[i];
  int base = boffs[blockIdx.x] + wexcl + (incl - T);
  int idx = blk * 1024 + tid * 4;
  int4 o4 = make_int4(base, base + e1, base + e2, base + e3);
  if (idx + 3 < N_NODES) {
    reinterpret_cast<int4*>(offs)[idx >> 2] = o4;
    reinterpret_cast<int4*>(cur)[idx >> 2] = o4;
  } else {
    if (idx + 0 < N_NODES) { offs[idx + 0] = o4.x; cur[idx + 0] = o4.x; }
    if (idx + 1 < N_NODES) { offs[idx + 1] = o4.y; cur[idx + 1] = o4.y; }
    if (idx + 2 < N_NODES) { offs[idx + 2] = o4.z; cur[idx + 2] = o4.z; }
    if (idx + 3 < N_NODES) { offs[idx + 3] = o4.w; cur[idx + 3] = o4.w; }
  }
}

__global__ void csr_scatter2(const int* __restrict__ ei0, const int* __restrict__ ei1,
                             int* __restrict__ cur0, int* __restrict__ cur1,
                             int* __restrict__ csr0, int* __restrict__ csr1)
{
  int e = blockIdx.x * blockDim.x + threadIdx.x;
  if (e >= 2 * EPRIME) return;
  int type = e >= EPRIME;
  int i = type ? e - EPRIME : e;
  const int* ei = type ? ei1 : ei0;
  int* cur = type ? cur1 : cur0;
  int* csr = type ? csr1 : csr0;
  int d = (i < E_EDGES) ? ei[E_EDGES + i] : (i - E_EDGES);
  int s = (i < E_EDGES) ? ei[i] : (i - E_EDGES);
  int pos = atomicAdd(&cur[d], 1);
  csr[pos] = s;
}

__global__ void csr_sort2(const int* __restrict__ offs0, int* __restrict__ csr0,
                          const int* __restrict__ offs1, int* __restrict__ csr1)
{
  int d = blockIdx.x * blockDim.x + threadIdx.x;
  if (d >= 2 * N_NODES) return;
  int type = d >= N_NODES;
  int i = type ? d - N_NODES : d;
  const int* offs = type ? offs1 : offs0;
  int* csr = type ? csr1 : csr0;
  int b = offs[i], e = offs[i + 1];
  for (int p = b + 1; p < e; p++) {
    int v = csr[p];
    int j = p - 1;
    while (j >= b && csr[j] > v) { csr[j + 1] = csr[j]; j--; }
    csr[j + 1] = v;
  }
}

// --------------------------------------------------------- DPP 8-lane reduce
__device__ __forceinline__ float dpp8_sum(float p) {
  p += __int_as_float(__builtin_amdgcn_update_dpp(0, __float_as_int(p), 0xB1, 0xF, 0xF, true));
  p += __int_as_float(__builtin_amdgcn_update_dpp(0, __float_as_int(p), 0x4E, 0xF, 0xF, true));
  p += __int_as_float(__builtin_amdgcn_update_dpp(0, __float_as_int(p), 0x141, 0xF, 0xF, true));
  return p;
}

__device__ __forceinline__ h8v leaky8(h8v x) {
  const _Float16 c = (_Float16)0.2f;
  h8v y = x * c;
#if __has_builtin(__builtin_elementwise_max)
  return __builtin_elementwise_max(x, y);
#else
  h8v r;
#pragma unroll
  for (int i = 0; i < 8; i++) r[i] = x[i] > y[i] ? x[i] : y[i];
  return r;
#endif
}

__device__ __forceinline__ float dot8(h8v e, const h2v* a) {
  h2v e0 = {e[0], e[1]}, e1 = {e[2], e[3]}, e2 = {e[4], e[5]}, e3 = {e[6], e[7]};
#if __has_builtin(__builtin_amdgcn_fdot2)
  float s = __builtin_amdgcn_fdot2(e0, a[0], 0.f, false);
  s = __builtin_amdgcn_fdot2(e1, a[1], s, false);
  s = __builtin_amdgcn_fdot2(e2, a[2], s, false);
  s = __builtin_amdgcn_fdot2(e3, a[3], s, false);
  return s;
#else
  float s = 0.f;
#pragma unroll
  for (int i = 0; i < 8; i++) s += (float)e[i] * (float)a[i >> 1][i & 1];
  return s;
#endif
}

// ---------------------------------------------- GATv2: dst-centric online SM
// one wave per dst; lanes 0-31 = even edges, 32-63 = odd; 4 edges in flight.
// Index-prefetch pipeline: next group's csr loads issue one iteration early,
// so the gather (dependent on the index) starts immediately at loop top
// instead of eating index-load latency serially.
__global__ __launch_bounds__(256) void gat_edge3(
    const _Float16* __restrict__ xlr,   // [MP,1024] fp16
    const int* __restrict__ offs0, const int* __restrict__ csr0,
    const int* __restrict__ offs1, const int* __restrict__ csr1,
    const float* __restrict__ att,      // [2*256] layer base
    const float* __restrict__ bias,     // [2*256] layer base
    ushort* __restrict__ out, int nblk_per_type)
{
  const int type = blockIdx.x >= nblk_per_type;
  const int bid = type ? blockIdx.x - nblk_per_type : blockIdx.x;
  const int wid = (bid * 256 + threadIdx.x) >> 6;
  if (wid >= N_NODES) return;
  const int lane = threadIdx.x & 63;
  const int half = lane >> 5, li = lane & 31;
  const int* offs = type ? offs1 : offs0;
  const int* csr  = type ? csr1 : csr0;
  const int xl_col = type ? 512 : 0;

  const float* ap = att + type * 256 + li * 8;
  h2v a[4];
#pragma unroll
  for (int i = 0; i < 4; i++) {
    a[i][0] = (_Float16)ap[2 * i];
    a[i][1] = (_Float16)ap[2 * i + 1];
  }
  const h8v xr = *reinterpret_cast<const h8v*>(xlr + (size_t)wid * 1024 + xl_col + 256 + li * 8);

  const int beg = offs[wid], end = offs[wid + 1];
  const float L2E = 1.44269504f;
  float m = -1e30f, den = 0.f;
  float acc[8];
#pragma unroll
  for (int i = 0; i < 8; i++) acc[i] = 0.f;

  const int ng = (end - beg + 3) >> 2;
  int j0 = beg + half, j1 = j0 + 2;
  int s0 = csr[j0 < end ? j0 : beg];
  int s1 = csr[j1 < end ? j1 : beg];
  for (int g = 0; g < ng; g++) {
    const bool v0 = j0 < end, v1 = j1 < end;
    const int nj0 = j0 + 4, nj1 = j1 + 4;
    const int ns0 = csr[nj0 < end ? nj0 : beg];   // prefetch next group
    const int ns1 = csr[nj1 < end ? nj1 : beg];
    const h8v hs0 = *reinterpret_cast<const h8v*>(xlr + (size_t)s0 * 1024 + xl_col + li * 8);
    const h8v hs1 = *reinterpret_cast<const h8v*>(xlr + (size_t)s1 * 1024 + xl_col + li * 8);
    float p0 = dpp8_sum(dot8(leaky8(hs0 + xr), a));
    float p1 = dpp8_sum(dot8(leaky8(hs1 + xr), a));
    if (!v0) p0 = -INFINITY;
    if (!v1) p1 = -INFINITY;
    const float pm = fmaxf(p0, p1);
    if (__any(pm > m + 4.f)) {           // defer-max rescale (rare)
      const float nm = fmaxf(m, pm);
      const float so = exp2f((m - nm) * L2E);
      den *= so;
#pragma unroll
      for (int i = 0; i < 8; i++) acc[i] *= so;
      m = nm;
    }
    const float w0 = exp2f((p0 - m) * L2E);
    const float w1 = exp2f((p1 - m) * L2E);
    den += w0 + w1;
#pragma unroll
    for (int i = 0; i < 8; i++) {
      acc[i] = fmaf((float)hs0[i], w0, acc[i]);
      acc[i] = fmaf((float)hs1[i], w1, acc[i]);
    }
    j0 = nj0; j1 = nj1; s0 = ns0; s1 = ns1;
  }

  const float mo  = __shfl_xor(m, 32);
  const float dno = __shfl_xor(den, 32);
  const float ms = fmaxf(m, mo);
  const float fa = exp2f((m - ms) * L2E);
  const float fb = exp2f((mo - ms) * L2E);
  const float r = 1.f / (den * fa + dno * fb + 1e-16f);
  float of[8];
#pragma unroll
  for (int i = 0; i < 8; i++)
    of[i] = (acc[i] * fa + __shfl_xor(acc[i], 32) * fb) * r;

  if (half == 0) {
    const float* bp = bias + type * 256 + li * 8;
    uint4 o;
    uint pk[4];
#pragma unroll
    for (int i = 0; i < 4; i++) {
      const uint lo = f2bf(of[2 * i] + bp[2 * i]);
      const uint hi = f2bf(of[2 * i + 1] + bp[2 * i + 1]);
      pk[i] = lo | (hi << 16);
    }
    o.x = pk[0]; o.y = pk[1]; o.z = pk[2]; o.w = pk[3];
    *reinterpret_cast<uint4*>(out + (size_t)wid * 512 + type * 256 + li * 8) = o;
  }
}

// ----------------------------------------------------------------- launcher
extern "C" void kernel_launch(void* const* d_in, const int* in_sizes, int n_in,
                              void* d_out, int out_size, void* d_ws, size_t ws_size,
                              hipStream_t stream)
{
  const float* x        = (const float*)d_in[0];
  const int*   ei0      = (const int*)d_in[1];
  const int*   ei1      = (const int*)d_in[2];
  const float* pre_W0   = (const float*)d_in[3];
  const float* pre_b0   = (const float*)d_in[4];
  const float* pre_g0   = (const float*)d_in[5];
  const float* pre_be0  = (const float*)d_in[6];
  const float* pre_W1   = (const float*)d_in[7];
  const float* pre_b1   = (const float*)d_in[8];
  const float* pre_g1   = (const float*)d_in[9];
  const float* pre_be1  = (const float*)d_in[10];
  const float* gat_Wl   = (const float*)d_in[11];
  const float* gat_Wr   = (const float*)d_in[12];
  const float* gat_att  = (const float*)d_in[13];
  const float* gat_bias = (const float*)d_in[14];
  const float* proj_W   = (const float*)d_in[15];
  const float* proj_b   = (const float*)d_in[16];
  const float* head_W0  = (const float*)d_in[17];
  const float* head_b0  = (const float*)d_in[18];
  const float* head_W1  = (const float*)d_in[19];
  const float* head_b1  = (const float*)d_in[20];
  float* outp = (float*)d_out;

  // ---- workspace arena (all segments 16B-aligned)
  char* ws = (char*)d_ws;
  ushort* xlr_b = (ushort*)ws; ws += (size_t)MP * 1024 * 2;   // fp16 GAT input
  ushort* xb    = xlr_b;       // alias: bf16 cast of x (dead once layer0 GEMM runs)
  ushort* hb    = (ushort*)ws; ws += (size_t)MP * 256 * 2;
  ushort* outt  = (ushort*)ws; ws += (size_t)MP * 512 * 2;   // gat concat out
  float*  tmp   = (float*)outt;                               // alias: pre-LN f32 buf
  ushort* hbuf  = (ushort*)outt;                              // alias: head0 out
  ushort* W0t      = (ushort*)ws; ws += (size_t)256 * 1024 * 2;
  ushort* W1t      = (ushort*)ws; ws += (size_t)256 * 256 * 2;
  ushort* WcatT    = (ushort*)ws; ws += (size_t)LAYERS * 1024 * 256 * 2;
  ushort* projcatT = (ushort*)ws; ws += (size_t)LAYERS * 256 * 512 * 2;
  ushort* hW0t     = (ushort*)ws; ws += (size_t)256 * 256 * 2;
  ushort* hW1t     = (ushort*)ws; ws += (size_t)128 * 256 * 2;
  int* cnt0  = (int*)ws; ws += (size_t)NPAD * 4;
  int* cnt1  = (int*)ws; ws += (size_t)NPAD * 4;
  int* offs0 = (int*)ws; ws += (size_t)(N_NODES + 4) * 4;
  int* offs1 = (int*)ws; ws += (size_t)(N_NODES + 4) * 4;
  int* cur0  = (int*)ws; ws += (size_t)N_NODES * 4;
  int* cur1  = (int*)ws; ws += (size_t)N_NODES * 4;
  int* bsums = (int*)ws; ws += (size_t)128 * 4;
  int* boffs = (int*)ws; ws += (size_t)128 * 4;
  int* csr0  = (int*)ws; ws += (size_t)EPRIME * 4;
  int* csr1  = (int*)ws; ws += (size_t)EPRIME * 4;

  // ---- fused prep: wtrans + csr count + x cast (count/cast overlap)
  hipMemsetAsync(cnt0, 0, (size_t)2 * NPAD * 4, stream);   // cnt0+cnt1 contiguous
  prep_all<<<NWT + NCNT + NCAST, 256, 0, stream>>>(
      pre_W0, pre_W1, gat_Wl, gat_Wr, proj_W, head_W0, head_W1,
      W0t, W1t, WcatT, projcatT, hW0t, hW1t,
      ei0, ei1, cnt0, cnt1, x, xb);

  // ---- CSR finalize (deterministic via per-bucket sort)
  const int gE2 = (2 * EPRIME + 255) / 256;
  scan_p1<<<2 * SCAN_NBLK, 256, 0, stream>>>(cnt0, cnt1, bsums);
  scan_p2<<<1, 64, 0, stream>>>(bsums, boffs, offs0, offs1);
  scan_p3<<<2 * SCAN_NBLK, 256, 0, stream>>>(cnt0, cnt1, boffs, offs0, cur0, offs1, cur1);
  csr_scatter2<<<gE2, 256, 0, stream>>>(ei0, ei1, cur0, cur1, csr0, csr1);
  csr_sort2<<<(2 * N_NODES + 255) / 256, 256, 0, stream>>>(offs0, csr0, offs1, csr1);

  const dim3 blk(256);
  const int gy = MP / 128;   // 391
  const int gln = (N_NODES * 64 + 255) / 256;   // 12500

  // ---- preprocessor MLP (pre0 reads the L3-resident bf16 cast of x)
  gemm_k<<<dim3(4, gy), blk, 0, stream>>>(xb, W0t, 1024, N_NODES, 256,
                                          tmp, nullptr, pre_b0, nullptr, 0, 0);
  ln_relu<<<gln, 256, 0, stream>>>(tmp, hb, pre_g0, pre_be0, N_NODES);
  gemm_k<<<dim3(4, gy), blk, 0, stream>>>(hb, W1t, 256, N_NODES, 256,
                                          tmp, nullptr, pre_b1, nullptr, 0, 0);
  ln_relu<<<gln, 256, 0, stream>>>(tmp, hb, pre_g1, pre_be1, N_NODES);

  // ---- GNN layers
  for (int l = 0; l < LAYERS; l++) {
    gemm_k<<<dim3(16, gy), blk, 0, stream>>>(hb, WcatT + (size_t)l * 1024 * 256,
                                             256, N_NODES, 1024,
                                             nullptr, xlr_b, nullptr, nullptr, 0, 1);
    gat_edge3<<<2 * gln, 256, 0, stream>>>(
        (const _Float16*)xlr_b, offs0, csr0, offs1, csr1,
        gat_att  + (size_t)l * NTYPES * NHEAD * DHEAD,
        gat_bias + (size_t)l * NTYPES * HID,
        outt, gln);
    gemm_k<<<dim3(4, gy), blk, 0, stream>>>(
        outt, projcatT + (size_t)l * 256 * 512, 512, N_NODES, 256,
        nullptr, hb,
        proj_b + (size_t)(l * NTYPES + 0) * HID,
        proj_b + (size_t)(l * NTYPES + 1) * HID, 1, 0);
  }

  // ---- prediction head
  gemm_k<<<dim3(4, gy), blk, 0, stream>>>(hb, hW0t, 256, N_NODES, 256,
                                          nullptr, hbuf, head_b0, nullptr, 1, 0);
  gemm_k<<<dim3(1, gy), blk, 0, stream>>>(hbuf, hW1t, 256, N_NODES, OUT_DIM,
                                          outp, nullptr, head_b1, nullptr, 0, 0);
}

// Round 10
// 741.788 us; speedup vs baseline: 1.1006x; 1.0457x over previous
//
#include <hip/hip_runtime.h>
#include <hip/hip_bf16.h>
#include <math.h>

#define N_NODES 50000
#define MP      50048          // 391 * 128, padded row count
#define E_EDGES 500000
#define EPRIME  (E_EDGES + N_NODES)
#define HID     256
#define PRE_IN  1024
#define OUT_DIM 64
#define NHEAD   4
#define DHEAD   64
#define LAYERS  2
#define NTYPES  2

#define SCAN_NBLK 49                     // ceil(50000/1024)
#define NPAD      (SCAN_NBLK * 1024)     // 50176

typedef __attribute__((ext_vector_type(8))) short short8v;
typedef __attribute__((ext_vector_type(4))) float f32x4;
typedef _Float16 h2v __attribute__((ext_vector_type(2)));
typedef _Float16 h8v __attribute__((ext_vector_type(8)));

__device__ __forceinline__ ushort f2bf(float f) {
  uint u = __float_as_uint(f);
  u += 0x7FFF + ((u >> 16) & 1);          // RNE
  return (ushort)(u >> 16);
}
__device__ __forceinline__ float bf2f(ushort u) {
  return __uint_as_float(((uint)u) << 16);
}

// ------------------------------------------------------------- bf16 MFMA GEMM
// C[M,N] = op(A[M,K] @ Bt[N,K]^T + bias(+bias2)); A,Bt bf16 K-major, rows padded.
// BM=128, BN=64, BK=32; 4 waves, wave-tile 64x32 (acc[4][2], 8 MFMA/K-step).
// R6-proven form: global_load_lds staging + __syncthreads 2-barrier loop.
// T1: bijective XCD-chunked blockIdx swizzle (m204).
// LDS layout byte = row*64 + (kc ^ ((row>>1)&3))*16 (XOR swizzle both sides).
__global__ __launch_bounds__(256) void gemm_k(
    const ushort* __restrict__ A,
    const ushort* __restrict__ Bt,
    int K, int M, int N,
    float*  __restrict__ Cf,          // f32 out (or null)
    ushort* __restrict__ Cb,          // 16-bit out (or null)
    const float* __restrict__ bias,   // [N] or null
    const float* __restrict__ bias2,  // [N] or null (added too)
    int do_relu, int out_f16)         // out_f16: Cb holds fp16 instead of bf16
{
  __shared__ ushort As[128 * 32];     // 8 KB
  __shared__ ushort Bs[64 * 32];      // 4 KB
  const int tid = threadIdx.x;
  const int l   = tid & 63;
  const int w   = tid >> 6;
  const int wm  = w & 1;              // row half (64 rows)
  const int wn  = w >> 1;             // col quarter (32 cols)

  // ---- T1: bijective XCD-chunked swizzle (m204)
  const int nwg  = gridDim.x * gridDim.y;
  const int orig = blockIdx.y * gridDim.x + blockIdx.x;
  const int qq   = nwg >> 3, rr = nwg & 7;
  const int xcd  = orig & 7;
  const int wgid = ((xcd < rr) ? xcd * (qq + 1) : rr * (qq + 1) + (xcd - rr) * qq)
                   + (orig >> 3);
  const int bm = (wgid / gridDim.x) * 128;
  const int bn = (wgid % gridDim.x) * 64;

  f32x4 acc[4][2];
#pragma unroll
  for (int m = 0; m < 4; m++)
#pragma unroll
    for (int n = 0; n < 2; n++) acc[m][n] = (f32x4){0.f, 0.f, 0.f, 0.f};

  const int srow  = l >> 2;   // 0..15
  const int sslot = l & 3;    // kc slot
  const int nt    = K >> 5;

  // A staging geometry (2 rows per thread)
  int  arow[2], akc[2];
  uint aoff[2];
#pragma unroll
  for (int i = 0; i < 2; i++) {
    arow[i] = w * 32 + i * 16 + srow;
    akc[i]  = sslot ^ ((arow[i] >> 1) & 3);
    aoff[i] = (uint)arow[i] * 64 + (uint)sslot * 16;
  }
  // B staging: one 16B slot per thread, dest = tid*16 (wave-linear)
  const int brow  = tid >> 2;        // 0..63
  const int bslot = tid & 3;
  const int bkc   = bslot ^ ((brow >> 1) & 3);

  for (int t = 0; t < nt; t++) {
    const int k0 = t << 5;
    {
      const ushort* gb = Bt + (size_t)(bn + brow) * K + k0 + bkc * 8;
      __builtin_amdgcn_global_load_lds(
          (const __attribute__((address_space(1))) uint*)gb,
          (__attribute__((address_space(3))) uint*)((char*)Bs + tid * 16), 16, 0, 0);
    }
#pragma unroll
    for (int i = 0; i < 2; i++) {
      const ushort* ga = A + (size_t)(bm + arow[i]) * K + k0 + akc[i] * 8;
      __builtin_amdgcn_global_load_lds(
          (const __attribute__((address_space(1))) uint*)ga,
          (__attribute__((address_space(3))) uint*)((char*)As + aoff[i]), 16, 0, 0);
    }
    __syncthreads();

    short8v a[4], b[2];
#pragma unroll
    for (int m = 0; m < 4; m++) {
      const int row = wm * 64 + m * 16 + (l & 15);
      const int kc  = (l >> 4) ^ ((row >> 1) & 3);
      a[m] = *(const short8v*)((const char*)As + row * 64 + kc * 16);
    }
#pragma unroll
    for (int n = 0; n < 2; n++) {
      const int row = wn * 32 + n * 16 + (l & 15);
      const int kc  = (l >> 4) ^ ((row >> 1) & 3);
      b[n] = *(const short8v*)((const char*)Bs + row * 64 + kc * 16);
    }
#pragma unroll
    for (int m = 0; m < 4; m++)
#pragma unroll
      for (int n = 0; n < 2; n++)
        acc[m][n] = __builtin_amdgcn_mfma_f32_16x16x32_bf16(a[m], b[n], acc[m][n], 0, 0, 0);
    __syncthreads();
  }

  // epilogue: C/D map col=lane&15, row=(lane>>4)*4+reg
  const int crow0 = bm + wm * 64 + (l >> 4) * 4;
  const int ccol0 = bn + wn * 32 + (l & 15);
#pragma unroll
  for (int m = 0; m < 4; m++) {
#pragma unroll
    for (int j = 0; j < 4; j++) {
      const int grow = crow0 + m * 16 + j;
      if (grow < M) {
#pragma unroll
        for (int n = 0; n < 2; n++) {
          const int gcol = ccol0 + n * 16;
          if (gcol < N) {
            float v = acc[m][n][j];
            if (bias)  v += bias[gcol];
            if (bias2) v += bias2[gcol];
            if (do_relu) v = fmaxf(v, 0.f);
            if (Cf) Cf[(size_t)grow * N + gcol] = v;
            else if (out_f16) {
              _Float16 hv = (_Float16)v;
              Cb[(size_t)grow * N + gcol] = *(ushort*)&hv;
            } else {
              Cb[(size_t)grow * N + gcol] = f2bf(v);
            }
          }
        }
      }
    }
  }
}

// ------------------------------------------------------------ LayerNorm+ReLU
__global__ void ln_relu(const float* __restrict__ in, ushort* __restrict__ out,
                        const float* __restrict__ g, const float* __restrict__ be, int n)
{
  int gid = blockIdx.x * blockDim.x + threadIdx.x;
  int row = gid >> 6;
  int lane = threadIdx.x & 63;
  if (row >= n) return;
  float4 v = *reinterpret_cast<const float4*>(in + (size_t)row * HID + lane * 4);
  float s = v.x + v.y + v.z + v.w;
  float ss = v.x * v.x + v.y * v.y + v.z * v.z + v.w * v.w;
#pragma unroll
  for (int o = 1; o < 64; o <<= 1) { s += __shfl_xor(s, o); ss += __shfl_xor(ss, o); }
  float mu = s * (1.f / 256.f);
  float var = ss * (1.f / 256.f) - mu * mu;
  float inv = rsqrtf(var + 1e-5f);
  float4 gg = *reinterpret_cast<const float4*>(g + lane * 4);
  float4 bb = *reinterpret_cast<const float4*>(be + lane * 4);
  ushort4 o4;
  o4.x = f2bf(fmaxf((v.x - mu) * inv * gg.x + bb.x, 0.f));
  o4.y = f2bf(fmaxf((v.y - mu) * inv * gg.y + bb.y, 0.f));
  o4.z = f2bf(fmaxf((v.z - mu) * inv * gg.z + bb.z, 0.f));
  o4.w = f2bf(fmaxf((v.w - mu) * inv * gg.w + bb.w, 0.f));
  *reinterpret_cast<ushort4*>(out + (size_t)row * HID + lane * 4) = o4;
}

// -------------------- fused prep: x cast + csr_count + wtrans (one launch)
// Regions INTERLEAVED by blockIdx % 3 (R9 post-mortem: contiguous region
// ranges serialized through dispatch order -- the BW-bound cast only started
// after ~9000 latency-bound wtrans/count blocks drained; 133us vs ~60us floor).
// region 0: x f32 -> bf16 streaming cast (the real 307 MB of traffic)
// region 1: csr in-degree count (atomic, latency-bound -> hides under cast)
// region 2: weight transpose/cast (uncoalesced reads, latency-bound -> hides)
#define WSEG0 262144              // W0t   [256][1024]
#define WSEG1 (WSEG0 + 65536)     // W1t   [256][256]
#define WSEG2 (WSEG1 + 524288)    // WcatT [L][1024][256]
#define WSEG3 (WSEG2 + 262144)    // projcatT [L][256][512]
#define WSEG4 (WSEG3 + 65536)     // hW0t  [256][256]
#define WSEG5 (WSEG4 + 32768)     // hW1t  [128][256]
#define NREG  4736                // max(wtrans 4736, count 4297, cast)
#define CAST_UNITS (N_NODES * 1024 / 8)    // 6.4M short8 units

__global__ void prep_all(const float* __restrict__ pre_W0, const float* __restrict__ pre_W1,
                         const float* __restrict__ Wl, const float* __restrict__ Wr,
                         const float* __restrict__ proj_W,
                         const float* __restrict__ head_W0, const float* __restrict__ head_W1,
                         ushort* __restrict__ W0t, ushort* __restrict__ W1t,
                         ushort* __restrict__ WcatT, ushort* __restrict__ projcatT,
                         ushort* __restrict__ hW0t, ushort* __restrict__ hW1t,
                         const int* __restrict__ ei0, const int* __restrict__ ei1,
                         int* __restrict__ cnt0, int* __restrict__ cnt1,
                         const float* __restrict__ x, ushort* __restrict__ xb)
{
  const int region = blockIdx.x % 3;
  const int idx = blockIdx.x / 3;
  if (region == 0) {
    // streaming cast, grid-stride over NREG*256 threads
    const float4* xf = (const float4*)x;
    short8v* xo = (short8v*)xb;
    for (size_t i = (size_t)idx * 256 + threadIdx.x;
         i < (size_t)CAST_UNITS; i += (size_t)NREG * 256) {
      float4 v0 = xf[2 * i];
      float4 v1 = xf[2 * i + 1];
      short8v s;
      s[0] = (short)f2bf(v0.x); s[1] = (short)f2bf(v0.y);
      s[2] = (short)f2bf(v0.z); s[3] = (short)f2bf(v0.w);
      s[4] = (short)f2bf(v1.x); s[5] = (short)f2bf(v1.y);
      s[6] = (short)f2bf(v1.z); s[7] = (short)f2bf(v1.w);
      xo[i] = s;
    }
  } else if (region == 1) {
    int e = idx * 256 + threadIdx.x;
    if (e < 2 * EPRIME) {
      int type = e >= EPRIME;
      int i = type ? e - EPRIME : e;
      const int* ei = type ? ei1 : ei0;
      int* cnt = type ? cnt1 : cnt0;
      int d = (i < E_EDGES) ? ei[E_EDGES + i] : (i - E_EDGES);
      atomicAdd(&cnt[d], 1);
    }
  } else {
    int i = idx * 256 + threadIdx.x;
    if (i < WSEG0) {
      int nrow = i >> 10, k = i & 1023;
      W0t[i] = f2bf(pre_W0[(size_t)k * 256 + nrow]);
    } else if (i < WSEG1) {
      int j = i - WSEG0;
      int nrow = j >> 8, k = j & 255;
      W1t[j] = f2bf(pre_W1[(size_t)k * 256 + nrow]);
    } else if (i < WSEG2) {
      int j = i - WSEG1;
      int l = j >> 18;
      int rem = j & 262143;
      int c = rem >> 8, k = rem & 255;
      int t = c >> 9, half = (c >> 8) & 1, cc = c & 255;
      const float* W = half ? Wr : Wl;
      WcatT[j] = f2bf(W[(((size_t)l * NTYPES + t) * 256 + k) * 256 + cc]);
    } else if (i < WSEG3) {
      int j = i - WSEG2;
      int l = j >> 17;
      int rem = j & 131071;
      int n = rem >> 9, k = rem & 511;
      int t = k >> 8, kk = k & 255;
      projcatT[j] = f2bf(proj_W[(((size_t)l * NTYPES + t) * 256 + kk) * 256 + n]);
    } else if (i < WSEG4) {
      int j = i - WSEG3;
      int nrow = j >> 8, k = j & 255;
      hW0t[j] = f2bf(head_W0[(size_t)k * 256 + nrow]);
    } else if (i < WSEG5) {
      int j = i - WSEG4;
      int nrow = j >> 8, k = j & 255;
      hW1t[j] = (nrow < OUT_DIM) ? f2bf(head_W1[(size_t)k * OUT_DIM + nrow]) : (ushort)0;
    }
  }
}

// --- hierarchical exclusive scan over cnt0,cnt1 (padded to NPAD with zeros)
__global__ __launch_bounds__(256) void scan_p1(const int* __restrict__ cnt0,
                                               const int* __restrict__ cnt1,
                                               int* __restrict__ bsums)
{
  int type = blockIdx.x >= SCAN_NBLK;
  int blk = type ? blockIdx.x - SCAN_NBLK : blockIdx.x;
  const int* cnt = type ? cnt1 : cnt0;
  int4 v = reinterpret_cast<const int4*>(cnt)[blk * 256 + threadIdx.x];
  int s = v.x + v.y + v.z + v.w;
#pragma unroll
  for (int o = 1; o < 64; o <<= 1) s += __shfl_xor(s, o);
  __shared__ int wt[4];
  if ((threadIdx.x & 63) == 0) wt[threadIdx.x >> 6] = s;
  __syncthreads();
  if (threadIdx.x == 0) bsums[blockIdx.x] = wt[0] + wt[1] + wt[2] + wt[3];
}

__global__ void scan_p2(const int* __restrict__ bsums, int* __restrict__ boffs,
                        int* __restrict__ offs0, int* __restrict__ offs1)
{
  int t = threadIdx.x;
  if (t < 2) {
    int run = 0;
    for (int i = 0; i < SCAN_NBLK; i++) {
      boffs[t * SCAN_NBLK + i] = run;
      run += bsums[t * SCAN_NBLK + i];
    }
  }
  if (t == 2) offs0[N_NODES] = EPRIME;
  if (t == 3) offs1[N_NODES] = EPRIME;
}

__global__ __launch_bounds__(256) void scan_p3(
    const int* __restrict__ cnt0, const int* __restrict__ cnt1,
    const int* __restrict__ boffs,
    int* __restrict__ offs0, int* __restrict__ cur0,
    int* __restrict__ offs1, int* __restrict__ cur1)
{
  int type = blockIdx.x >= SCAN_NBLK;
  int blk = type ? blockIdx.x - SCAN_NBLK : blockIdx.x;
  const int* cnt = type ? cnt1 : cnt0;
  int* offs = type ? offs1 : offs0;
  int* cur  = type ? cur1 : cur0;
  const int tid = threadIdx.x, lane = tid & 63, wv = tid >> 6;
  int4 v = reinterpret_cast<const int4*>(cnt)[blk * 256 + tid];
  int e1 = v.x, e2 = e1 + v.y, e3 = e2 + v.z, T = e3 + v.w;
  int incl = T;
#pragma unroll
  for (int o = 1; o < 64; o <<= 1) {
    int nb = __shfl_up(incl, o);
    if (lane >= o) incl += nb;
  }
  __shared__ int wt[4];
  if (lane == 63) wt[wv] = incl;
  __syncthreads();
  int wexcl = 0;
  for (int i = 0; i < wv; i++) wexcl += wt[i];
  int base = boffs[blockIdx.x] + wexcl + (incl - T);
  int idx = blk * 1024 + tid * 4;
  int4 o4 = make_int4(base, base + e1, base + e2, base + e3);
  if (idx + 3 < N_NODES) {
    reinterpret_cast<int4*>(offs)[idx >> 2] = o4;
    reinterpret_cast<int4*>(cur)[idx >> 2] = o4;
  } else {
    if (idx + 0 < N_NODES) { offs[idx + 0] = o4.x; cur[idx + 0] = o4.x; }
    if (idx + 1 < N_NODES) { offs[idx + 1] = o4.y; cur[idx + 1] = o4.y; }
    if (idx + 2 < N_NODES) { offs[idx + 2] = o4.z; cur[idx + 2] = o4.z; }
    if (idx + 3 < N_NODES) { offs[idx + 3] = o4.w; cur[idx + 3] = o4.w; }
  }
}

__global__ void csr_scatter2(const int* __restrict__ ei0, const int* __restrict__ ei1,
                             int* __restrict__ cur0, int* __restrict__ cur1,
                             int* __restrict__ csr0, int* __restrict__ csr1)
{
  int e = blockIdx.x * blockDim.x + threadIdx.x;
  if (e >= 2 * EPRIME) return;
  int type = e >= EPRIME;
  int i = type ? e - EPRIME : e;
  const int* ei = type ? ei1 : ei0;
  int* cur = type ? cur1 : cur0;
  int* csr = type ? csr1 : csr0;
  int d = (i < E_EDGES) ? ei[E_EDGES + i] : (i - E_EDGES);
  int s = (i < E_EDGES) ? ei[i] : (i - E_EDGES);
  int pos = atomicAdd(&cur[d], 1);
  csr[pos] = s;
}

__global__ void csr_sort2(const int* __restrict__ offs0, int* __restrict__ csr0,
                          const int* __restrict__ offs1, int* __restrict__ csr1)
{
  int d = blockIdx.x * blockDim.x + threadIdx.x;
  if (d >= 2 * N_NODES) return;
  int type = d >= N_NODES;
  int i = type ? d - N_NODES : d;
  const int* offs = type ? offs1 : offs0;
  int* csr = type ? csr1 : csr0;
  int b = offs[i], e = offs[i + 1];
  for (int p = b + 1; p < e; p++) {
    int v = csr[p];
    int j = p - 1;
    while (j >= b && csr[j] > v) { csr[j + 1] = csr[j]; j--; }
    csr[j + 1] = v;
  }
}

// --------------------------------------------------------- DPP 8-lane reduce
__device__ __forceinline__ float dpp8_sum(float p) {
  p += __int_as_float(__builtin_amdgcn_update_dpp(0, __float_as_int(p), 0xB1, 0xF, 0xF, true));
  p += __int_as_float(__builtin_amdgcn_update_dpp(0, __float_as_int(p), 0x4E, 0xF, 0xF, true));
  p += __int_as_float(__builtin_amdgcn_update_dpp(0, __float_as_int(p), 0x141, 0xF, 0xF, true));
  return p;
}

__device__ __forceinline__ h8v leaky8(h8v x) {
  const _Float16 c = (_Float16)0.2f;
  h8v y = x * c;
#if __has_builtin(__builtin_elementwise_max)
  return __builtin_elementwise_max(x, y);
#else
  h8v r;
#pragma unroll
  for (int i = 0; i < 8; i++) r[i] = x[i] > y[i] ? x[i] : y[i];
  return r;
#endif
}

__device__ __forceinline__ float dot8(h8v e, const h2v* a) {
  h2v e0 = {e[0], e[1]}, e1 = {e[2], e[3]}, e2 = {e[4], e[5]}, e3 = {e[6], e[7]};
#if __has_builtin(__builtin_amdgcn_fdot2)
  float s = __builtin_amdgcn_fdot2(e0, a[0], 0.f, false);
  s = __builtin_amdgcn_fdot2(e1, a[1], s, false);
  s = __builtin_amdgcn_fdot2(e2, a[2], s, false);
  s = __builtin_amdgcn_fdot2(e3, a[3], s, false);
  return s;
#else
  float s = 0.f;
#pragma unroll
  for (int i = 0; i < 8; i++) s += (float)e[i] * (float)a[i >> 1][i & 1];
  return s;
#endif
}

// ---------------------------------------------- GATv2: dst-centric online SM
// one wave per dst; lanes 0-31 = even edges, 32-63 = odd; 4 edges in flight.
// Index-prefetch pipeline: next group's csr loads issue one iteration early.
__global__ __launch_bounds__(256) void gat_edge3(
    const _Float16* __restrict__ xlr,   // [MP,1024] fp16
    const int* __restrict__ offs0, const int* __restrict__ csr0,
    const int* __restrict__ offs1, const int* __restrict__ csr1,
    const float* __restrict__ att,      // [2*256] layer base
    const float* __restrict__ bias,     // [2*256] layer base
    ushort* __restrict__ out, int nblk_per_type)
{
  const int type = blockIdx.x >= nblk_per_type;
  const int bid = type ? blockIdx.x - nblk_per_type : blockIdx.x;
  const int wid = (bid * 256 + threadIdx.x) >> 6;
  if (wid >= N_NODES) return;
  const int lane = threadIdx.x & 63;
  const int half = lane >> 5, li = lane & 31;
  const int* offs = type ? offs1 : offs0;
  const int* csr  = type ? csr1 : csr0;
  const int xl_col = type ? 512 : 0;

  const float* ap = att + type * 256 + li * 8;
  h2v a[4];
#pragma unroll
  for (int i = 0; i < 4; i++) {
    a[i][0] = (_Float16)ap[2 * i];
    a[i][1] = (_Float16)ap[2 * i + 1];
  }
  const h8v xr = *reinterpret_cast<const h8v*>(xlr + (size_t)wid * 1024 + xl_col + 256 + li * 8);

  const int beg = offs[wid], end = offs[wid + 1];
  const float L2E = 1.44269504f;
  float m = -1e30f, den = 0.f;
  float acc[8];
#pragma unroll
  for (int i = 0; i < 8; i++) acc[i] = 0.f;

  const int ng = (end - beg + 3) >> 2;
  int j0 = beg + half, j1 = j0 + 2;
  int s0 = csr[j0 < end ? j0 : beg];
  int s1 = csr[j1 < end ? j1 : beg];
  for (int g = 0; g < ng; g++) {
    const bool v0 = j0 < end, v1 = j1 < end;
    const int nj0 = j0 + 4, nj1 = j1 + 4;
    const int ns0 = csr[nj0 < end ? nj0 : beg];   // prefetch next group
    const int ns1 = csr[nj1 < end ? nj1 : beg];
    const h8v hs0 = *reinterpret_cast<const h8v*>(xlr + (size_t)s0 * 1024 + xl_col + li * 8);
    const h8v hs1 = *reinterpret_cast<const h8v*>(xlr + (size_t)s1 * 1024 + xl_col + li * 8);
    float p0 = dpp8_sum(dot8(leaky8(hs0 + xr), a));
    float p1 = dpp8_sum(dot8(leaky8(hs1 + xr), a));
    if (!v0) p0 = -INFINITY;
    if (!v1) p1 = -INFINITY;
    const float pm = fmaxf(p0, p1);
    if (__any(pm > m + 4.f)) {           // defer-max rescale (rare)
      const float nm = fmaxf(m, pm);
      const float so = exp2f((m - nm) * L2E);
      den *= so;
#pragma unroll
      for (int i = 0; i < 8; i++) acc[i] *= so;
      m = nm;
    }
    const float w0 = exp2f((p0 - m) * L2E);
    const float w1 = exp2f((p1 - m) * L2E);
    den += w0 + w1;
#pragma unroll
    for (int i = 0; i < 8; i++) {
      acc[i] = fmaf((float)hs0[i], w0, acc[i]);
      acc[i] = fmaf((float)hs1[i], w1, acc[i]);
    }
    j0 = nj0; j1 = nj1; s0 = ns0; s1 = ns1;
  }

  const float mo  = __shfl_xor(m, 32);
  const float dno = __shfl_xor(den, 32);
  const float ms = fmaxf(m, mo);
  const float fa = exp2f((m - ms) * L2E);
  const float fb = exp2f((mo - ms) * L2E);
  const float r = 1.f / (den * fa + dno * fb + 1e-16f);
  float of[8];
#pragma unroll
  for (int i = 0; i < 8; i++)
    of[i] = (acc[i] * fa + __shfl_xor(acc[i], 32) * fb) * r;

  if (half == 0) {
    const float* bp = bias + type * 256 + li * 8;
    uint4 o;
    uint pk[4];
#pragma unroll
    for (int i = 0; i < 4; i++) {
      const uint lo = f2bf(of[2 * i] + bp[2 * i]);
      const uint hi = f2bf(of[2 * i + 1] + bp[2 * i + 1]);
      pk[i] = lo | (hi << 16);
    }
    o.x = pk[0]; o.y = pk[1]; o.z = pk[2]; o.w = pk[3];
    *reinterpret_cast<uint4*>(out + (size_t)wid * 512 + type * 256 + li * 8) = o;
  }
}

// ----------------------------------------------------------------- launcher
extern "C" void kernel_launch(void* const* d_in, const int* in_sizes, int n_in,
                              void* d_out, int out_size, void* d_ws, size_t ws_size,
                              hipStream_t stream)
{
  const float* x        = (const float*)d_in[0];
  const int*   ei0      = (const int*)d_in[1];
  const int*   ei1      = (const int*)d_in[2];
  const float* pre_W0   = (const float*)d_in[3];
  const float* pre_b0   = (const float*)d_in[4];
  const float* pre_g0   = (const float*)d_in[5];
  const float* pre_be0  = (const float*)d_in[6];
  const float* pre_W1   = (const float*)d_in[7];
  const float* pre_b1   = (const float*)d_in[8];
  const float* pre_g1   = (const float*)d_in[9];
  const float* pre_be1  = (const float*)d_in[10];
  const float* gat_Wl   = (const float*)d_in[11];
  const float* gat_Wr   = (const float*)d_in[12];
  const float* gat_att  = (const float*)d_in[13];
  const float* gat_bias = (const float*)d_in[14];
  const float* proj_W   = (const float*)d_in[15];
  const float* proj_b   = (const float*)d_in[16];
  const float* head_W0  = (const float*)d_in[17];
  const float* head_b0  = (const float*)d_in[18];
  const float* head_W1  = (const float*)d_in[19];
  const float* head_b1  = (const float*)d_in[20];
  float* outp = (float*)d_out;

  // ---- workspace arena (all segments 16B-aligned)
  char* ws = (char*)d_ws;
  ushort* xlr_b = (ushort*)ws; ws += (size_t)MP * 1024 * 2;   // fp16 GAT input
  ushort* xb    = xlr_b;       // alias: bf16 cast of x (dead once layer0 GEMM runs)
  ushort* hb    = (ushort*)ws; ws += (size_t)MP * 256 * 2;
  ushort* outt  = (ushort*)ws; ws += (size_t)MP * 512 * 2;   // gat concat out
  float*  tmp   = (float*)outt;                               // alias: pre-LN f32 buf
  ushort* hbuf  = (ushort*)outt;                              // alias: head0 out
  ushort* W0t      = (ushort*)ws; ws += (size_t)256 * 1024 * 2;
  ushort* W1t      = (ushort*)ws; ws += (size_t)256 * 256 * 2;
  ushort* WcatT    = (ushort*)ws; ws += (size_t)LAYERS * 1024 * 256 * 2;
  ushort* projcatT = (ushort*)ws; ws += (size_t)LAYERS * 256 * 512 * 2;
  ushort* hW0t     = (ushort*)ws; ws += (size_t)256 * 256 * 2;
  ushort* hW1t     = (ushort*)ws; ws += (size_t)128 * 256 * 2;
  int* cnt0  = (int*)ws; ws += (size_t)NPAD * 4;
  int* cnt1  = (int*)ws; ws += (size_t)NPAD * 4;
  int* offs0 = (int*)ws; ws += (size_t)(N_NODES + 4) * 4;
  int* offs1 = (int*)ws; ws += (size_t)(N_NODES + 4) * 4;
  int* cur0  = (int*)ws; ws += (size_t)N_NODES * 4;
  int* cur1  = (int*)ws; ws += (size_t)N_NODES * 4;
  int* bsums = (int*)ws; ws += (size_t)128 * 4;
  int* boffs = (int*)ws; ws += (size_t)128 * 4;
  int* csr0  = (int*)ws; ws += (size_t)EPRIME * 4;
  int* csr1  = (int*)ws; ws += (size_t)EPRIME * 4;

  // ---- fused prep: cast + count + wtrans, regions interleaved by bid%3
  hipMemsetAsync(cnt0, 0, (size_t)2 * NPAD * 4, stream);   // cnt0+cnt1 contiguous
  prep_all<<<3 * NREG, 256, 0, stream>>>(
      pre_W0, pre_W1, gat_Wl, gat_Wr, proj_W, head_W0, head_W1,
      W0t, W1t, WcatT, projcatT, hW0t, hW1t,
      ei0, ei1, cnt0, cnt1, x, xb);

  // ---- CSR finalize (deterministic via per-bucket sort)
  const int gE2 = (2 * EPRIME + 255) / 256;
  scan_p1<<<2 * SCAN_NBLK, 256, 0, stream>>>(cnt0, cnt1, bsums);
  scan_p2<<<1, 64, 0, stream>>>(bsums, boffs, offs0, offs1);
  scan_p3<<<2 * SCAN_NBLK, 256, 0, stream>>>(cnt0, cnt1, boffs, offs0, cur0, offs1, cur1);
  csr_scatter2<<<gE2, 256, 0, stream>>>(ei0, ei1, cur0, cur1, csr0, csr1);
  csr_sort2<<<(2 * N_NODES + 255) / 256, 256, 0, stream>>>(offs0, csr0, offs1, csr1);

  const dim3 blk(256);
  const int gy = MP / 128;   // 391
  const int gln = (N_NODES * 64 + 255) / 256;   // 12500

  // ---- preprocessor MLP (pre0 reads the L3-resident bf16 cast of x)
  gemm_k<<<dim3(4, gy), blk, 0, stream>>>(xb, W0t, 1024, N_NODES, 256,
                                          tmp, nullptr, pre_b0, nullptr, 0, 0);
  ln_relu<<<gln, 256, 0, stream>>>(tmp, hb, pre_g0, pre_be0, N_NODES);
  gemm_k<<<dim3(4, gy), blk, 0, stream>>>(hb, W1t, 256, N_NODES, 256,
                                          tmp, nullptr, pre_b1, nullptr, 0, 0);
  ln_relu<<<gln, 256, 0, stream>>>(tmp, hb, pre_g1, pre_be1, N_NODES);

  // ---- GNN layers
  for (int l = 0; l < LAYERS; l++) {
    gemm_k<<<dim3(16, gy), blk, 0, stream>>>(hb, WcatT + (size_t)l * 1024 * 256,
                                             256, N_NODES, 1024,
                                             nullptr, xlr_b, nullptr, nullptr, 0, 1);
    gat_edge3<<<2 * gln, 256, 0, stream>>>(
        (const _Float16*)xlr_b, offs0, csr0, offs1, csr1,
        gat_att  + (size_t)l * NTYPES * NHEAD * DHEAD,
        gat_bias + (size_t)l * NTYPES * HID,
        outt, gln);
    gemm_k<<<dim3(4, gy), blk, 0, stream>>>(
        outt, projcatT + (size_t)l * 256 * 512, 512, N_NODES, 256,
        nullptr, hb,
        proj_b + (size_t)(l * NTYPES + 0) * HID,
        proj_b + (size_t)(l * NTYPES + 1) * HID, 1, 0);
  }

  // ---- prediction head
  gemm_k<<<dim3(4, gy), blk, 0, stream>>>(hb, hW0t, 256, N_NODES, 256,
                                          nullptr, hbuf, head_b0, nullptr, 1, 0);
  gemm_k<<<dim3(1, gy), blk, 0, stream>>>(hbuf, hW1t, 256, N_NODES, OUT_DIM,
                                          outp, nullptr, head_b1, nullptr, 0, 0);
}